// Round 1
// baseline (952.606 us; speedup 1.0000x reference)
//
#include <hip/hip_runtime.h>
#include <math.h>

// Problem: B=16, DIM=64, RANK=32, H=W=128, E=4, K=2, BINS=8, FREQ_DIM=64, KS=7
// Pipeline: routing (GAP + FFT radial energy MLP, softmax, top-2) then 4 experts:
//  e0/e2: frequency-domain radial filter (rfft2/irfft2, linear -> project in freq domain)
//  e1: dw3x3 -> gelu -> dw3x3 ; e3: dw7x7 -> gelu -> avgpool3
// out = sum_e gate[b,e] * (P2 (body*silu(P1 x)) + x)  => gatesum*x + sum gated contributions.

namespace {

struct cpx { float x, y; };

__device__ __forceinline__ cpx cmul(cpx a, cpx b){ return {a.x*b.x - a.y*b.y, a.x*b.y + a.y*b.x}; }

__device__ __forceinline__ cpx tw(int k, float invN){
  float s, c;
  sincosf(-6.283185307179586f * (float)k * invN, &s, &c);
  return {c, s};
}

__device__ __forceinline__ int br6(int l){ return (int)(__brev((unsigned)l) >> 26); }

// 128-pt DIF FFT across one wave: lane holds a=in[l], b=in[l+64].
// Output: a = F[2*br6(l)], b = F[2*br6(l)+1].
__device__ __forceinline__ void fft128(cpx &a, cpx &b, int lane){
  cpx u{a.x + b.x, a.y + b.y};
  cpx v{a.x - b.x, a.y - b.y};
  v = cmul(v, tw(lane, 1.0f/128.0f));
  a = u; b = v;
  #pragma unroll
  for (int m = 32; m >= 1; m >>= 1){
    float pax = __shfl_xor(a.x, m);
    float pay = __shfl_xor(a.y, m);
    float pbx = __shfl_xor(b.x, m);
    float pby = __shfl_xor(b.y, m);
    cpx w = tw(lane & (m-1), 1.0f/(float)(2*m));
    if (lane & m){
      cpx ta{pax - a.x, pay - a.y};
      cpx tb{pbx - b.x, pby - b.y};
      a = cmul(ta, w);
      b = cmul(tb, w);
    } else {
      a.x += pax; a.y += pay;
      b.x += pbx; b.y += pby;
    }
  }
}

// ---------------- kernels ----------------

__global__ __launch_bounds__(256) void k_mean(const float* __restrict__ x, float* __restrict__ xmean){
  int bc = blockIdx.x; int t = threadIdx.x;
  const float* p = x + (size_t)bc * 16384;
  float s = 0.f;
  for (int i = t; i < 16384; i += 256) s += p[i];
  __shared__ float red[256];
  red[t] = s; __syncthreads();
  for (int k = 128; k > 0; k >>= 1){ if (t < k) red[t] += red[t+k]; __syncthreads(); }
  if (t == 0) xmean[bc] = red[0] * (1.0f/16384.0f);
}

// rfft over W for each (b,c,h). X layout: [bc][j(0..64)][h], float2.
__global__ __launch_bounds__(256) void k_rowfft(const float* __restrict__ x, float2* __restrict__ X){
  int wid = blockIdx.x * 4 + (threadIdx.x >> 6);
  int lane = threadIdx.x & 63;
  int h = wid & 127, bc = wid >> 7;
  const float* row = x + (size_t)wid * 128;
  cpx a{row[lane], 0.f}, b{row[lane+64], 0.f};
  fft128(a, b, lane);
  float2* Xbc = X + (size_t)bc * (65*128);
  int j0 = 2*br6(lane);
  if (j0 <= 64)   Xbc[j0*128 + h]     = make_float2(a.x, a.y);
  if (j0+1 <= 64) Xbc[(j0+1)*128 + h] = make_float2(b.x, b.y);
}

// complex FFT over H, in place, per (bc, j).
__global__ __launch_bounds__(256) void k_colfft(float2* __restrict__ X){
  int wid = blockIdx.x * 4 + (threadIdx.x >> 6);
  int lane = threadIdx.x & 63;
  int bc = wid / 65, j = wid - bc*65;
  float2* col = X + ((size_t)bc*65 + j) * 128;
  float2 z0 = col[lane], z1 = col[lane+64];
  cpx a{z0.x, z0.y}, b{z1.x, z1.y};
  fft128(a, b, lane);
  int i0 = 2*br6(lane);
  col[i0]   = make_float2(a.x, a.y);
  col[i0+1] = make_float2(b.x, b.y);
}

// radial energy histogram per (b,c); Hermitian symmetry: j in 1..63 weight 2.
__global__ __launch_bounds__(256) void k_energy(const float2* __restrict__ X, float* __restrict__ part){
  int bc = blockIdx.x; int t = threadIdx.x;
  const float2* P = X + (size_t)bc * (65*128);
  float e[9];
  float step = sqrtf(8192.0f) * 0.125f;   // matches jnp.linspace(0, dist.max(), 9)
  #pragma unroll
  for (int k = 0; k <= 8; k++) e[k] = step * (float)k;
  float acc[8] = {0,0,0,0,0,0,0,0};
  for (int idx = t; idx < 65*128; idx += 256){
    int j = idx >> 7, i = idx & 127;
    float2 z = P[idx];
    float mag = sqrtf(z.x*z.x + z.y*z.y) * (1.0f/16384.0f);  // norm='forward'
    float wgt = (j == 0 || j == 64) ? 1.0f : 2.0f;
    float dy = (float)(i - 64), dx = (float)(j - 64);
    float d = sqrtf(dy*dy + dx*dx);
    #pragma unroll
    for (int k = 0; k < 8; k++)
      if (d >= e[k] && d < e[k+1]) acc[k] += wgt * mag;
  }
  __shared__ float red[256];
  for (int k = 0; k < 8; k++){
    red[t] = acc[k]; __syncthreads();
    for (int s2 = 128; s2 > 0; s2 >>= 1){ if (t < s2) red[t] += red[t+s2]; __syncthreads(); }
    if (t == 0) part[bc*8 + k] = red[0];
    __syncthreads();
  }
}

__global__ __launch_bounds__(128) void k_routing(const float* __restrict__ xmean, const float* __restrict__ part,
    const float* __restrict__ noise, const float* __restrict__ gate_w,
    const float* __restrict__ fg_w1, const float* __restrict__ fg_b1, const float* __restrict__ fg_w2,
    float* __restrict__ gates, float* __restrict__ gsum){
  __shared__ float femb[16][8];
  __shared__ float hid[16][64];
  __shared__ float lgt[16][4];
  int t = threadIdx.x;
  {
    int b = t >> 3, k = t & 7;
    float s = 0.f;
    for (int c = 0; c < 64; c++) s += part[(b*64 + c)*8 + k];
    femb[b][k] = s * (1.0f/64.0f);
  }
  __syncthreads();
  for (int idx = t; idx < 16*64; idx += 128){
    int b = idx >> 6, f = idx & 63;
    float s = fg_b1[f];
    for (int k = 0; k < 8; k++) s += femb[b][k] * fg_w1[f*8 + k];
    hid[b][f] = fmaxf(s, 0.f);
  }
  __syncthreads();
  if (t < 64){
    int b = t >> 2, e = t & 3;
    float s = 0.f;
    for (int c = 0; c < 64; c++) s += xmean[b*64 + c] * gate_w[e*64 + c];
    for (int f = 0; f < 64; f++) s += hid[b][f] * fg_w2[e*64 + f];
    lgt[b][e] = s + noise[b*4 + e] * 0.25f;   // NOISE_STD = 1/E
  }
  __syncthreads();
  if (t < 16){
    int b = t;
    float m = fmaxf(fmaxf(lgt[b][0], lgt[b][1]), fmaxf(lgt[b][2], lgt[b][3]));
    float p[4]; float sum = 0.f;
    for (int e = 0; e < 4; e++){ p[e] = expf(lgt[b][e] - m); sum += p[e]; }
    for (int e = 0; e < 4; e++) p[e] /= sum;
    int i1 = 0;
    for (int e = 1; e < 4; e++) if (p[e] > p[i1]) i1 = e;   // strict > : ties -> lowest idx (lax.top_k)
    int i2 = -1;
    for (int e = 0; e < 4; e++){ if (e == i1) continue; if (i2 < 0 || p[e] > p[i2]) i2 = e; }
    for (int e = 0; e < 4; e++) gates[b*4 + e] = (e == i1 || e == i2) ? p[e] : 0.f;
    gsum[b] = p[i1] + p[i2];
  }
}

__global__ __launch_bounds__(256) void k_init_out(const float4* __restrict__ x4, const float* __restrict__ gsum,
    float4* __restrict__ out4){
  int i = blockIdx.x * 256 + threadIdx.x;
  int b = i >> 18;                     // 64*16384/4 = 2^18 float4 per b
  float g = gsum[b];
  float4 v = x4[i];
  out4[i] = make_float4(v.x*g, v.y*g, v.z*g, v.w*g);
}

// Y[b][r][j][i] = filt(i,j)/16384 * sum_c P0[r,c] X[b][c][j][i]   (gated per b)
__global__ __launch_bounds__(256) void k_projfreq(const float2* __restrict__ X, const float* __restrict__ P0,
    float2* __restrict__ Y, const float* __restrict__ gates, int e,
    const float* __restrict__ gainp, const float* __restrict__ decayp, float cmax){
  int b = blockIdx.z;
  if (gates[b*4 + e] == 0.f) return;
  int j = blockIdx.y;
  int i0 = blockIdx.x * 64;
  int t = threadIdx.x;
  __shared__ float2 sx[64][64];
  __shared__ float w0[2048];
  for (int i = t; i < 2048; i += 256) w0[i] = P0[i];
  for (int idx = t; idx < 4096; idx += 256){
    int c = idx >> 6, ii = idx & 63;
    sx[c][ii] = X[(((size_t)(b*64 + c))*65 + j)*128 + i0 + ii];
  }
  __syncthreads();
  int ii = t & 63, rg = t >> 6;
  int i = i0 + ii;
  float gain = *gainp, decay = *decayp;
  float fy = (float)(i < 64 ? i : i - 128) * (1.0f/128.0f);
  float fx = (float)j * (1.0f/128.0f);
  float fg = sqrtf(fy*fy + fx*fx);
  float filt = (1.0f - expf(-gain*fg)) * expf(-decay*fg);
  filt = fminf(fmaxf(filt, 0.0f), cmax) * (1.0f/16384.0f);  // fold ortho*ortho norm
  for (int r = rg*8; r < rg*8 + 8; r++){
    float ax = 0.f, ay = 0.f;
    for (int c = 0; c < 64; c++){
      float wv = w0[r*64 + c];
      float2 xv = sx[c][ii];
      ax += wv * xv.x; ay += wv * xv.y;
    }
    Y[(((size_t)(b*32 + r))*65 + j)*128 + i] = make_float2(ax*filt, ay*filt);
  }
}

// inverse complex FFT over i (H axis), in place, per (b,r,j). ifft = conj(fft(conj(.)))
__global__ __launch_bounds__(256) void k_icolfft(float2* __restrict__ Y, const float* __restrict__ gates, int e){
  int wid = blockIdx.x * 4 + (threadIdx.x >> 6);
  int lane = threadIdx.x & 63;
  int b = wid / 2080; int rem = wid - b*2080; int r = rem / 65; int j = rem - r*65;
  if (gates[b*4 + e] == 0.f) return;
  float2* col = Y + (((size_t)(b*32 + r))*65 + j) * 128;
  float2 z0 = col[lane], z1 = col[lane+64];
  cpx a{z0.x, -z0.y}, bb{z1.x, -z1.y};
  fft128(a, bb, lane);
  int i0 = 2*br6(lane);
  col[i0]   = make_float2(a.x, -a.y);
  col[i0+1] = make_float2(bb.x, -bb.y);
}

// irfft over W per (b,r,h): Hermitian-extend j, inverse, keep real part.
__global__ __launch_bounds__(256) void k_irowfft(const float2* __restrict__ Y, float* __restrict__ body,
    const float* __restrict__ gates, int e){
  int wid = blockIdx.x * 4 + (threadIdx.x >> 6);
  int lane = threadIdx.x & 63;
  int b = wid >> 12; int r = (wid >> 7) & 31; int h = wid & 127;
  if (gates[b*4 + e] == 0.f) return;
  const float2* Z = Y + ((size_t)(b*32 + r)) * (65*128);
  float2 z0 = Z[lane*128 + h];
  cpx a{z0.x, -z0.y};                  // conj(F[lane])
  cpx bb;
  if (lane == 0){
    float2 z1 = Z[64*128 + h];
    bb = {z1.x, -z1.y};                // conj(F[64])
  } else {
    float2 z1 = Z[(64 - lane)*128 + h];
    bb = {z1.x, z1.y};                 // conj(conj(Z[64-l])) = Z[64-l]
  }
  fft128(a, bb, lane);
  float* op = body + (((size_t)(b*32 + r))*128 + h) * 128;
  int n0 = 2*br6(lane);
  op[n0]   = a.x;
  op[n0+1] = bb.x;
}

// A = P0 x (optional), G = silu(P1 x); gated per b.
__global__ __launch_bounds__(256) void k_proj(const float* __restrict__ x, const float* __restrict__ P0,
    const float* __restrict__ P1, float* __restrict__ A, float* __restrict__ G,
    const float* __restrict__ gates, int e, int doA){
  int b = blockIdx.y;
  if (gates[b*4 + e] == 0.f) return;
  int hw = blockIdx.x * 256 + threadIdx.x;
  int t = threadIdx.x;
  __shared__ float w0[2048], w1[2048];
  for (int i = t; i < 2048; i += 256){ w0[i] = P0[i]; w1[i] = P1[i]; }
  __syncthreads();
  float acc0[32], acc1[32];
  #pragma unroll
  for (int r = 0; r < 32; r++){ acc0[r] = 0.f; acc1[r] = 0.f; }
  const float* xb = x + ((size_t)b*64)*16384 + hw;
  for (int c = 0; c < 64; c++){
    float xv = xb[(size_t)c*16384];
    #pragma unroll
    for (int r = 0; r < 32; r++){
      acc0[r] += w0[r*64 + c] * xv;
      acc1[r] += w1[r*64 + c] * xv;
    }
  }
  for (int r = 0; r < 32; r++){
    size_t o = ((size_t)(b*32 + r))*16384 + hw;
    if (doA) A[o] = acc0[r];
    float v = acc1[r];
    G[o] = v / (1.0f + expf(-v));
  }
}

__global__ __launch_bounds__(256) void k_dwconv(const float* __restrict__ in, float* __restrict__ out,
    const float* __restrict__ wt, const float* __restrict__ bs, int ks, int pad, int dogelu,
    const float* __restrict__ gates, int e){
  int br_ = blockIdx.y; int b = br_ >> 5, r = br_ & 31;
  if (gates[b*4 + e] == 0.f) return;
  int p = blockIdx.x * 256 + threadIdx.x;
  int h = p >> 7, w = p & 127;
  const float* ip = in + ((size_t)br_ << 14);
  float acc = bs[r];
  for (int kh = 0; kh < ks; kh++){
    int ih = h + kh - pad;
    if ((unsigned)ih >= 128u) continue;
    for (int kw = 0; kw < ks; kw++){
      int iw = w + kw - pad;
      if ((unsigned)iw >= 128u) continue;
      acc += wt[r*ks*ks + kh*ks + kw] * ip[ih*128 + iw];
    }
  }
  if (dogelu) acc = 0.5f*acc*(1.0f + erff(acc*0.70710678118654752f));
  out[((size_t)br_ << 14) + p] = acc;
}

__global__ __launch_bounds__(256) void k_avgpool(const float* __restrict__ in, float* __restrict__ out,
    const float* __restrict__ gates, int e){
  int br_ = blockIdx.y; int b = br_ >> 5;
  if (gates[b*4 + e] == 0.f) return;
  int p = blockIdx.x * 256 + threadIdx.x;
  int h = p >> 7, w = p & 127;
  const float* ip = in + ((size_t)br_ << 14);
  float acc = 0.f;
  for (int kh = -1; kh <= 1; kh++){
    int ih = h + kh; if ((unsigned)ih >= 128u) continue;
    for (int kw = -1; kw <= 1; kw++){
      int iw = w + kw; if ((unsigned)iw >= 128u) continue;
      acc += ip[ih*128 + iw];
    }
  }
  out[((size_t)br_ << 14) + p] = acc * (1.0f/9.0f);
}

// out[b,c,:] += gate * sum_r P2[c,r] * (body[b,r,:] * G[b,r,:])
__global__ __launch_bounds__(256) void k_combine(const float* __restrict__ body, const float* __restrict__ G,
    const float* __restrict__ P2, float* __restrict__ out, const float* __restrict__ gates, int e){
  int b = blockIdx.y;
  float gv = gates[b*4 + e];
  if (gv == 0.f) return;
  int hw = blockIdx.x * 256 + threadIdx.x;
  int t = threadIdx.x;
  __shared__ float st[32][256];
  __shared__ float w2[2048];
  for (int i = t; i < 2048; i += 256) w2[i] = P2[i];
  for (int r = 0; r < 32; r++){
    size_t o = ((size_t)(b*32 + r))*16384 + hw;
    st[r][t] = body[o] * G[o];
  }
  __syncthreads();
  for (int c = 0; c < 64; c++){
    float acc = 0.f;
    #pragma unroll
    for (int r = 0; r < 32; r++) acc += w2[c*32 + r] * st[r][t];
    size_t o = ((size_t)(b*64 + c))*16384 + hw;
    out[o] += gv * acc;
  }
}

} // namespace

extern "C" void kernel_launch(void* const* d_in, const int* in_sizes, int n_in,
                              void* d_out, int out_size, void* d_ws, size_t ws_size,
                              hipStream_t stream) {
  (void)in_sizes; (void)n_in; (void)out_size; (void)ws_size;
  const float* x        = (const float*)d_in[0];
  const float* noise    = (const float*)d_in[1];
  const float* gate_w   = (const float*)d_in[2];
  const float* fg_w1    = (const float*)d_in[3];
  const float* fg_b1    = (const float*)d_in[4];
  const float* fg_w2    = (const float*)d_in[5];
  const float* proj0    = (const float*)d_in[6];
  const float* proj1    = (const float*)d_in[7];
  const float* proj2    = (const float*)d_in[8];
  const float* hg_gain  = (const float*)d_in[9];
  const float* hg_decay = (const float*)d_in[10];
  const float* hf_w1    = (const float*)d_in[11];
  const float* hf_b1    = (const float*)d_in[12];
  const float* hf_w2    = (const float*)d_in[13];
  const float* hf_b2    = (const float*)d_in[14];
  const float* lg_gain  = (const float*)d_in[15];
  const float* lg_decay = (const float*)d_in[16];
  const float* lf_w     = (const float*)d_in[17];
  const float* lf_b     = (const float*)d_in[18];
  float* out = (float*)d_out;

  // workspace layout (floats). A,G overlay X (X dead after both projfreq); conv tmp reuses Y0.
  float* ws = (float*)d_ws;
  float2* X = (float2*)ws;             // 17,039,360 floats = [1024][65][128] float2
  float*  A = ws;                      // 8,388,608 floats (overlays X, used after X dead)
  float*  G = ws + 8388608;            // 8,388,608 floats (overlays X tail)
  float*  Y0 = ws + 17039360;          // 8,519,680 floats ([16][32][65][128] float2) / conv tmp
  float*  Y2 = Y0 + 8519680;           // 8,519,680 floats
  float*  xmean = Y2 + 8519680;        // 1024
  float*  part  = xmean + 1024;        // 8192
  float*  gates = part + 8192;         // 64
  float*  gsum  = gates + 64;          // 16

  // ---- routing ----
  k_mean  <<<1024, 256, 0, stream>>>(x, xmean);
  k_rowfft<<<32768, 256, 0, stream>>>(x, X);
  k_colfft<<<16640, 256, 0, stream>>>(X);
  k_energy<<<1024, 256, 0, stream>>>(X, part);
  k_routing<<<1, 128, 0, stream>>>(xmean, part, noise, gate_w, fg_w1, fg_b1, fg_w2, gates, gsum);
  k_init_out<<<16384, 256, 0, stream>>>((const float4*)x, gsum, (float4*)out);

  // ---- frequency-domain projections (while X alive) ----
  k_projfreq<<<dim3(2,65,16), 256, 0, stream>>>(X, proj0 + 0*2048, (float2*)Y0, gates, 0, hg_gain, hg_decay, 3.0f);
  k_projfreq<<<dim3(2,65,16), 256, 0, stream>>>(X, proj0 + 2*2048, (float2*)Y2, gates, 2, lg_gain, lg_decay, 1.0f);

  // ---- expert 0 (HighFreqGlobal) ----
  k_icolfft<<<8320, 256, 0, stream>>>((float2*)Y0, gates, 0);
  k_irowfft<<<16384, 256, 0, stream>>>((const float2*)Y0, A, gates, 0);
  k_proj   <<<dim3(64,16), 256, 0, stream>>>(x, proj0 + 0*2048, proj1 + 0*2048, A, G, gates, 0, 0);
  k_combine<<<dim3(64,16), 256, 0, stream>>>(A, G, proj2 + 0*2048, out, gates, 0);

  // ---- expert 2 (LowFreqGlobal) ----
  k_icolfft<<<8320, 256, 0, stream>>>((float2*)Y2, gates, 2);
  k_irowfft<<<16384, 256, 0, stream>>>((const float2*)Y2, A, gates, 2);
  k_proj   <<<dim3(64,16), 256, 0, stream>>>(x, proj0 + 2*2048, proj1 + 2*2048, A, G, gates, 2, 0);
  k_combine<<<dim3(64,16), 256, 0, stream>>>(A, G, proj2 + 2*2048, out, gates, 2);

  // ---- expert 1 (HighFreqLocal: dw3 -> gelu -> dw3) ----
  k_proj   <<<dim3(64,16), 256, 0, stream>>>(x, proj0 + 1*2048, proj1 + 1*2048, A, G, gates, 1, 1);
  k_dwconv <<<dim3(64,512), 256, 0, stream>>>(A, Y0, hf_w1, hf_b1, 3, 1, 1, gates, 1);
  k_dwconv <<<dim3(64,512), 256, 0, stream>>>(Y0, A, hf_w2, hf_b2, 3, 1, 0, gates, 1);
  k_combine<<<dim3(64,16), 256, 0, stream>>>(A, G, proj2 + 1*2048, out, gates, 1);

  // ---- expert 3 (LowFreqLocal: dw7 -> gelu -> avgpool3) ----
  k_proj   <<<dim3(64,16), 256, 0, stream>>>(x, proj0 + 3*2048, proj1 + 3*2048, A, G, gates, 3, 1);
  k_dwconv <<<dim3(64,512), 256, 0, stream>>>(A, Y0, lf_w, lf_b, 7, 3, 1, gates, 3);
  k_avgpool<<<dim3(64,512), 256, 0, stream>>>(Y0, A, gates, 3);
  k_combine<<<dim3(64,16), 256, 0, stream>>>(A, G, proj2 + 3*2048, out, gates, 3);
}

// Round 2
// 816.499 us; speedup vs baseline: 1.1667x; 1.1667x over previous
//
#include <hip/hip_runtime.h>
#include <math.h>

// B=16, DIM=64, RANK=32, H=W=128, E=4, K=2, BINS=8, FREQ_DIM=64, KS=7
// Round 2: fused unrolled conv experts; fused fwd FFT2+energy (packed Nyquist,
// 64KB LDS, coalesced X writes); fused inverse FFT2 (in-place body over Y).

namespace {

struct cpx { float x, y; };
struct Tw7 { cpx t[7]; };

__device__ __forceinline__ cpx cmul(cpx a, cpx b){ return {a.x*b.x - a.y*b.y, a.x*b.y + a.y*b.x}; }

__device__ __forceinline__ cpx tw(int k, float invN){
  float s, c;
  sincosf(-6.283185307179586f * (float)k * invN, &s, &c);
  return {c, s};
}

__device__ __forceinline__ void init_tw(Tw7 &T, int lane){
  T.t[0] = tw(lane,      1.0f/128.0f);
  T.t[1] = tw(lane & 31, 1.0f/64.0f);
  T.t[2] = tw(lane & 15, 1.0f/32.0f);
  T.t[3] = tw(lane & 7,  1.0f/16.0f);
  T.t[4] = tw(lane & 3,  1.0f/8.0f);
  T.t[5] = tw(lane & 1,  1.0f/4.0f);
  T.t[6] = {1.0f, 0.0f};
}

__device__ __forceinline__ int br6(int l){ return (int)(__brev((unsigned)l) >> 26); }

// 128-pt DIF FFT across one wave: lane holds a=in[l], b=in[l+64].
// Output: a = F[2*br6(l)], b = F[2*br6(l)+1].
__device__ __forceinline__ void fft128(cpx &a, cpx &b, int lane, const Tw7 &T){
  cpx u{a.x + b.x, a.y + b.y};
  cpx v{a.x - b.x, a.y - b.y};
  v = cmul(v, T.t[0]);
  a = u; b = v;
  int s = 1;
  #pragma unroll
  for (int m = 32; m >= 1; m >>= 1, s++){
    float pax = __shfl_xor(a.x, m);
    float pay = __shfl_xor(a.y, m);
    float pbx = __shfl_xor(b.x, m);
    float pby = __shfl_xor(b.y, m);
    cpx w = T.t[s];
    if (lane & m){
      cpx ta{pax - a.x, pay - a.y};
      cpx tb{pbx - b.x, pby - b.y};
      a = cmul(ta, w);
      b = cmul(tb, w);
    } else {
      a.x += pax; a.y += pay;
      b.x += pbx; b.y += pby;
    }
  }
}

#define LIDX(j,i) ((((j) << 7)) | (((i) ^ ((j) & 31)) & 127))

__device__ __forceinline__ float gelu_exact(float v){
  return 0.5f * v * (1.0f + erff(v * 0.70710678118654752f));
}

// ---------------- kernels ----------------

__global__ __launch_bounds__(256) void k_mean(const float* __restrict__ x, float* __restrict__ xmean){
  int bc = blockIdx.x; int t = threadIdx.x;
  const float* p = x + (size_t)bc * 16384;
  float s = 0.f;
  for (int i = t; i < 16384; i += 256) s += p[i];
  __shared__ float red[256];
  red[t] = s; __syncthreads();
  for (int k = 128; k > 0; k >>= 1){ if (t < k) red[t] += red[t+k]; __syncthreads(); }
  if (t == 0) xmean[bc] = red[0] * (1.0f/16384.0f);
}

// Fused 2-D rFFT per (b,c) + radial energy partials. X out: [bc][j0..64][i], float2.
__global__ __launch_bounds__(256) void k_fft2fwd(const float* __restrict__ x, float2* __restrict__ X,
                                                 float* __restrict__ part_w){
  __shared__ float re[8192];
  __shared__ float im[8192];
  int bc = blockIdx.x; int t = threadIdx.x;
  int lane = t & 63, w = t >> 6;
  Tw7 T; init_tw(T, lane);
  const float* img = x + (size_t)bc * 16384;

  // row FFTs (real input): wave w does rows w*32..w*32+31
  for (int k = 0; k < 32; k++){
    int h = w*32 + k;
    cpx a{img[h*128 + lane], 0.f};
    cpx b{img[h*128 + lane + 64], 0.f};
    fft128(a, b, lane, T);
    int j0 = 2*br6(lane), j1 = j0 + 1;
    if (j0 == 0){ re[LIDX(0,h)] = a.x; }
    else if (j0 < 64){ re[LIDX(j0,h)] = a.x; im[LIDX(j0,h)] = a.y; }
    else if (j0 == 64){ im[LIDX(0,h)] = a.x; }   // Nyquist col (real) packed into im[0]
    if (j1 < 64){ re[LIDX(j1,h)] = b.x; im[LIDX(j1,h)] = b.y; }
  }
  __syncthreads();

  // column FFTs: 64 cols (col 0 packed = F0 + i*F64)
  for (int jj = w; jj < 64; jj += 4){
    cpx a{re[LIDX(jj,lane)],    im[LIDX(jj,lane)]};
    cpx b{re[LIDX(jj,lane+64)], im[LIDX(jj,lane+64)]};
    fft128(a, b, lane, T);
    int i0 = 2*br6(lane);
    re[LIDX(jj,i0)]   = a.x; im[LIDX(jj,i0)]   = a.y;
    re[LIDX(jj,i0+1)] = b.x; im[LIDX(jj,i0+1)] = b.y;
  }
  __syncthreads();

  // radial energy (full-fft2 Hermitian weighting), from LDS
  float edges[9];
  float step = sqrtf(8192.0f) * 0.125f;
  #pragma unroll
  for (int k = 0; k <= 8; k++) edges[k] = step * (float)k;
  float acc[8] = {0,0,0,0,0,0,0,0};
  for (int idx = t; idx < 64*128; idx += 256){
    int j = idx >> 7, i = idx & 127;
    if (j == 0){
      float cr = re[LIDX(0,i)], ci = im[LIDX(0,i)];
      int in_ = (128 - i) & 127;
      float dr = re[LIDX(0,in_)], di = im[LIDX(0,in_)];
      float x0r = 0.5f*(cr + dr), x0i = 0.5f*(ci - di);
      float x6r = 0.5f*(ci + di), x6i = 0.5f*(dr - cr);
      float m0 = sqrtf(x0r*x0r + x0i*x0i) * (1.0f/16384.0f);
      float m6 = sqrtf(x6r*x6r + x6i*x6i) * (1.0f/16384.0f);
      float dyv = (float)(i - 64);
      float d0 = sqrtf(dyv*dyv + 4096.0f);   // j=0: dx=-64
      float d6 = fabsf(dyv);                 // j=64: dx=0
      #pragma unroll
      for (int k = 0; k < 8; k++){
        if (d0 >= edges[k] && d0 < edges[k+1]) acc[k] += m0;
        if (d6 >= edges[k] && d6 < edges[k+1]) acc[k] += m6;
      }
    } else {
      float zr = re[LIDX(j,i)], zi = im[LIDX(j,i)];
      float mag = sqrtf(zr*zr + zi*zi) * (2.0f/16384.0f);  // Hermitian weight 2
      float dy = (float)(i - 64), dx = (float)(j - 64);
      float d = sqrtf(dy*dy + dx*dx);
      #pragma unroll
      for (int k = 0; k < 8; k++)
        if (d >= edges[k] && d < edges[k+1]) acc[k] += mag;
    }
  }
  #pragma unroll
  for (int k = 0; k < 8; k++){
    float v = acc[k];
    for (int off = 32; off > 0; off >>= 1) v += __shfl_xor(v, off);
    if (lane == 0) part_w[(bc*4 + w)*8 + k] = v;
  }

  // coalesced X write-out
  float2* Xo = X + (size_t)bc * (65*128);
  for (int idx = t; idx < 65*128; idx += 256){
    int j = idx >> 7, i = idx & 127;
    float2 v;
    if (j == 0){
      float cr = re[LIDX(0,i)], ci = im[LIDX(0,i)];
      int in_ = (128 - i) & 127;
      float dr = re[LIDX(0,in_)], di = im[LIDX(0,in_)];
      v = make_float2(0.5f*(cr + dr), 0.5f*(ci - di));
    } else if (j == 64){
      float cr = re[LIDX(0,i)], ci = im[LIDX(0,i)];
      int in_ = (128 - i) & 127;
      float dr = re[LIDX(0,in_)], di = im[LIDX(0,in_)];
      v = make_float2(0.5f*(ci + di), 0.5f*(dr - cr));
    } else {
      v = make_float2(re[LIDX(j,i)], im[LIDX(j,i)]);
    }
    Xo[idx] = v;
  }
}

__global__ __launch_bounds__(128) void k_routing(const float* __restrict__ xmean, const float* __restrict__ part_w,
    const float* __restrict__ noise, const float* __restrict__ gate_w,
    const float* __restrict__ fg_w1, const float* __restrict__ fg_b1, const float* __restrict__ fg_w2,
    float* __restrict__ gates, float* __restrict__ gsum){
  __shared__ float femb[16][8];
  __shared__ float hid[16][64];
  __shared__ float lgt[16][4];
  int t = threadIdx.x;
  {
    int b = t >> 3, k = t & 7;
    float s = 0.f;
    for (int c = 0; c < 64; c++)
      for (int w = 0; w < 4; w++)
        s += part_w[((b*64 + c)*4 + w)*8 + k];
    femb[b][k] = s * (1.0f/64.0f);
  }
  __syncthreads();
  for (int idx = t; idx < 16*64; idx += 128){
    int b = idx >> 6, f = idx & 63;
    float s = fg_b1[f];
    for (int k = 0; k < 8; k++) s += femb[b][k] * fg_w1[f*8 + k];
    hid[b][f] = fmaxf(s, 0.f);
  }
  __syncthreads();
  if (t < 64){
    int b = t >> 2, e = t & 3;
    float s = 0.f;
    for (int c = 0; c < 64; c++) s += xmean[b*64 + c] * gate_w[e*64 + c];
    for (int f = 0; f < 64; f++) s += hid[b][f] * fg_w2[e*64 + f];
    lgt[b][e] = s + noise[b*4 + e] * 0.25f;
  }
  __syncthreads();
  if (t < 16){
    int b = t;
    float m = fmaxf(fmaxf(lgt[b][0], lgt[b][1]), fmaxf(lgt[b][2], lgt[b][3]));
    float p[4]; float sum = 0.f;
    for (int e = 0; e < 4; e++){ p[e] = expf(lgt[b][e] - m); sum += p[e]; }
    for (int e = 0; e < 4; e++) p[e] /= sum;
    int i1 = 0;
    for (int e = 1; e < 4; e++) if (p[e] > p[i1]) i1 = e;
    int i2 = -1;
    for (int e = 0; e < 4; e++){ if (e == i1) continue; if (i2 < 0 || p[e] > p[i2]) i2 = e; }
    for (int e = 0; e < 4; e++) gates[b*4 + e] = (e == i1 || e == i2) ? p[e] : 0.f;
    gsum[b] = p[i1] + p[i2];
  }
}

__global__ __launch_bounds__(256) void k_init_out(const float4* __restrict__ x4, const float* __restrict__ gsum,
    float4* __restrict__ out4){
  int i = blockIdx.x * 256 + threadIdx.x;
  int b = i >> 18;
  float g = gsum[b];
  float4 v = x4[i];
  out4[i] = make_float4(v.x*g, v.y*g, v.z*g, v.w*g);
}

// Y[b][r][j][i] = filt(i,j)/16384 * sum_c P0[r,c] X[b][c][j][i]   (gated per b)
__global__ __launch_bounds__(256) void k_projfreq(const float2* __restrict__ X, const float* __restrict__ P0,
    float2* __restrict__ Y, const float* __restrict__ gates, int e,
    const float* __restrict__ gainp, const float* __restrict__ decayp, float cmax){
  int b = blockIdx.z;
  if (gates[b*4 + e] == 0.f) return;
  int j = blockIdx.y;
  int i0 = blockIdx.x * 64;
  int t = threadIdx.x;
  __shared__ float2 sx[64][64];
  __shared__ float w0[2048];
  for (int i = t; i < 2048; i += 256) w0[i] = P0[i];
  for (int idx = t; idx < 4096; idx += 256){
    int c = idx >> 6, ii = idx & 63;
    sx[c][ii] = X[(((size_t)(b*64 + c))*65 + j)*128 + i0 + ii];
  }
  __syncthreads();
  int ii = t & 63, rg = t >> 6;
  int i = i0 + ii;
  float gain = *gainp, decay = *decayp;
  float fy = (float)(i < 64 ? i : i - 128) * (1.0f/128.0f);
  float fx = (float)j * (1.0f/128.0f);
  float fg = sqrtf(fy*fy + fx*fx);
  float filt = (1.0f - expf(-gain*fg)) * expf(-decay*fg);
  filt = fminf(fmaxf(filt, 0.0f), cmax) * (1.0f/16384.0f);
  for (int r = rg*8; r < rg*8 + 8; r++){
    float ax = 0.f, ay = 0.f;
    for (int c = 0; c < 64; c++){
      float wv = w0[r*64 + c];
      float2 xv = sx[c][ii];
      ax += wv * xv.x; ay += wv * xv.y;
    }
    Y[(((size_t)(b*32 + r))*65 + j)*128 + i] = make_float2(ax*filt, ay*filt);
  }
}

// Fused inverse 2-D FFT per (b,r); body written IN PLACE over the Y slot.
__global__ __launch_bounds__(256) void k_ifft2(float2* __restrict__ Y, const float* __restrict__ gates, int e){
  int br_ = blockIdx.x; int b = br_ >> 5;
  if (gates[b*4 + e] == 0.f) return;
  __shared__ float re[8192];
  __shared__ float im[8192];
  int t = threadIdx.x; int lane = t & 63, w = t >> 6;
  Tw7 T; init_tw(T, lane);
  float2* Yb = Y + (size_t)br_ * (65*128);

  // load; row 0 packed: P[i] = Y[0][i] + i*Y[64][i]
  for (int idx = t; idx < 64*128; idx += 256){
    int j = idx >> 7, i = idx & 127;
    if (j == 0){
      float2 y0 = Yb[i];
      float2 y6 = Yb[64*128 + i];
      re[LIDX(0,i)] = y0.x - y6.y;
      im[LIDX(0,i)] = y0.y + y6.x;
    } else {
      float2 v = Yb[j*128 + i];
      re[LIDX(j,i)] = v.x;
      im[LIDX(j,i)] = v.y;
    }
  }
  __syncthreads();

  // inverse column FFTs (unnormalized): conj -> fft -> conj
  for (int jj = w; jj < 64; jj += 4){
    cpx a{re[LIDX(jj,lane)],    -im[LIDX(jj,lane)]};
    cpx b{re[LIDX(jj,lane+64)], -im[LIDX(jj,lane+64)]};
    fft128(a, b, lane, T);
    int i0 = 2*br6(lane);
    re[LIDX(jj,i0)]   = a.x; im[LIDX(jj,i0)]   = -a.y;
    re[LIDX(jj,i0+1)] = b.x; im[LIDX(jj,i0+1)] = -b.y;
  }
  __syncthreads();

  // inverse row transform (irfft over j), Hermitian extension; real out
  float* body = (float*)Yb;
  for (int k = 0; k < 32; k++){
    int h = w*32 + k;
    cpx a, bb;
    if (lane == 0){
      a  = {re[LIDX(0,h)], 0.f};   // Z[0] real
      bb = {im[LIDX(0,h)], 0.f};   // Z[64] real
    } else {
      a  = {re[LIDX(lane,h)], -im[LIDX(lane,h)]};
      bb = {re[LIDX(64-lane,h)], im[LIDX(64-lane,h)]};
    }
    fft128(a, bb, lane, T);
    int n0 = 2*br6(lane);
    body[h*128 + n0]     = a.x;
    body[h*128 + n0 + 1] = bb.x;
  }
}

// A = P0 x (optional), G = silu(P1 x); gated per b.
__global__ __launch_bounds__(256) void k_proj(const float* __restrict__ x, const float* __restrict__ P0,
    const float* __restrict__ P1, float* __restrict__ A, float* __restrict__ G,
    const float* __restrict__ gates, int e, int doA){
  int b = blockIdx.y;
  if (gates[b*4 + e] == 0.f) return;
  int hw = blockIdx.x * 256 + threadIdx.x;
  int t = threadIdx.x;
  __shared__ float w0[2048], w1[2048];
  for (int i = t; i < 2048; i += 256){ w0[i] = P0[i]; w1[i] = P1[i]; }
  __syncthreads();
  float acc0[32], acc1[32];
  #pragma unroll
  for (int r = 0; r < 32; r++){ acc0[r] = 0.f; acc1[r] = 0.f; }
  const float* xb = x + ((size_t)b*64)*16384 + hw;
  for (int c = 0; c < 64; c++){
    float xv = xb[(size_t)c*16384];
    #pragma unroll
    for (int r = 0; r < 32; r++){
      acc0[r] += w0[r*64 + c] * xv;
      acc1[r] += w1[r*64 + c] * xv;
    }
  }
  for (int r = 0; r < 32; r++){
    size_t o = ((size_t)(b*32 + r))*16384 + hw;
    if (doA) A[o] = acc0[r];
    float v = acc1[r];
    G[o] = v / (1.0f + expf(-v));
  }
}

// Expert 1 fused: dw3 -> gelu -> dw3, LDS-tiled (16 out rows x 128)
__global__ __launch_bounds__(256) void k_conv3(const float* __restrict__ A, float* __restrict__ body,
    const float* __restrict__ w1g, const float* __restrict__ b1g,
    const float* __restrict__ w2g, const float* __restrict__ b2g,
    const float* __restrict__ gates){
  int br_ = blockIdx.y; int b = br_ >> 5, r = br_ & 31;
  if (gates[b*4 + 1] == 0.f) return;
  int h0 = blockIdx.x * 16;
  int t = threadIdx.x;
  __shared__ float sin_[20*130];
  __shared__ float st[18*130];
  for (int i = t; i < 20*130; i += 256) sin_[i] = 0.f;
  for (int i = t; i < 18*130; i += 256) st[i] = 0.f;
  float w1[9], w2[9];
  #pragma unroll
  for (int k = 0; k < 9; k++){ w1[k] = w1g[r*9 + k]; w2[k] = w2g[r*9 + k]; }
  float b1 = b1g[r], b2 = b2g[r];
  __syncthreads();
  const float* ip = A + ((size_t)br_ << 14);
  for (int idx = t; idx < 20*128; idx += 256){
    int li = idx >> 7, ww = idx & 127;
    int ih = h0 - 2 + li;
    if (ih >= 0 && ih < 128) sin_[li*130 + 1 + ww] = ip[ih*128 + ww];
  }
  __syncthreads();
  for (int idx = t; idx < 18*128; idx += 256){
    int li = idx >> 7, ww = idx & 127;
    int hs = h0 - 1 + li;
    if (hs >= 0 && hs < 128){
      float acc = b1;
      #pragma unroll
      for (int kh = 0; kh < 3; kh++)
        #pragma unroll
        for (int kw = 0; kw < 3; kw++)
          acc += w1[kh*3 + kw] * sin_[(li + kh)*130 + ww + kw];
      st[li*130 + 1 + ww] = gelu_exact(acc);
    }
  }
  __syncthreads();
  float* op = body + ((size_t)br_ << 14);
  for (int idx = t; idx < 16*128; idx += 256){
    int li = idx >> 7, ww = idx & 127;
    int ho = h0 + li;
    float acc = b2;
    #pragma unroll
    for (int kh = 0; kh < 3; kh++)
      #pragma unroll
      for (int kw = 0; kw < 3; kw++)
        acc += w2[kh*3 + kw] * st[(li + kh)*130 + ww + kw];
    op[ho*128 + ww] = acc;
  }
}

// Expert 3 fused: dw7 -> gelu -> avgpool3 (count_include_pad)
__global__ __launch_bounds__(256) void k_conv7(const float* __restrict__ A, float* __restrict__ body,
    const float* __restrict__ wg, const float* __restrict__ bg,
    const float* __restrict__ gates){
  int br_ = blockIdx.y; int b = br_ >> 5, r = br_ & 31;
  if (gates[b*4 + 3] == 0.f) return;
  int h0 = blockIdx.x * 16;
  int t = threadIdx.x;
  __shared__ float sin_[24*134];
  __shared__ float st[18*134];
  __shared__ float wsh[49];
  for (int i = t; i < 24*134; i += 256) sin_[i] = 0.f;
  for (int i = t; i < 18*134; i += 256) st[i] = 0.f;
  if (t < 49) wsh[t] = wg[r*49 + t];
  float bias = bg[r];
  __syncthreads();
  const float* ip = A + ((size_t)br_ << 14);
  for (int idx = t; idx < 24*128; idx += 256){
    int li = idx >> 7, ww = idx & 127;
    int ih = h0 - 4 + li;
    if (ih >= 0 && ih < 128) sin_[li*134 + 3 + ww] = ip[ih*128 + ww];
  }
  __syncthreads();
  for (int idx = t; idx < 18*128; idx += 256){
    int li = idx >> 7, ww = idx & 127;
    int hs = h0 - 1 + li;
    if (hs >= 0 && hs < 128){
      float acc = bias;
      #pragma unroll
      for (int kh = 0; kh < 7; kh++)
        #pragma unroll
        for (int kw = 0; kw < 7; kw++)
          acc += wsh[kh*7 + kw] * sin_[(li + kh)*134 + ww + kw];
      st[li*134 + 1 + ww] = gelu_exact(acc);
    }
  }
  __syncthreads();
  float* op = body + ((size_t)br_ << 14);
  for (int idx = t; idx < 16*128; idx += 256){
    int li = idx >> 7, ww = idx & 127;
    int ho = h0 + li;
    float acc = 0.f;
    #pragma unroll
    for (int kh = 0; kh < 3; kh++)
      #pragma unroll
      for (int kw = 0; kw < 3; kw++)
        acc += st[(li + kh)*134 + ww + kw];
    op[ho*128 + ww] = acc * (1.0f/9.0f);
  }
}

// out[b,c,:] += gate * sum_r P2[c,r] * (body[b,r,:] * G[b,r,:]); body stride param
__global__ __launch_bounds__(256) void k_combine(const float* __restrict__ body, const float* __restrict__ G,
    const float* __restrict__ P2, float* __restrict__ out, const float* __restrict__ gates, int e, int bstride){
  int b = blockIdx.y;
  float gv = gates[b*4 + e];
  if (gv == 0.f) return;
  int hw = blockIdx.x * 256 + threadIdx.x;
  int t = threadIdx.x;
  __shared__ float st[32][256];
  __shared__ float w2[2048];
  for (int i = t; i < 2048; i += 256) w2[i] = P2[i];
  for (int r = 0; r < 32; r++){
    st[r][t] = body[((size_t)(b*32 + r))*bstride + hw] * G[((size_t)(b*32 + r))*16384 + hw];
  }
  __syncthreads();
  for (int c = 0; c < 64; c++){
    float acc = 0.f;
    #pragma unroll
    for (int r = 0; r < 32; r++) acc += w2[c*32 + r] * st[r][t];
    size_t o = ((size_t)(b*64 + c))*16384 + hw;
    out[o] += gv * acc;
  }
}

} // namespace

extern "C" void kernel_launch(void* const* d_in, const int* in_sizes, int n_in,
                              void* d_out, int out_size, void* d_ws, size_t ws_size,
                              hipStream_t stream) {
  (void)in_sizes; (void)n_in; (void)out_size; (void)ws_size;
  const float* x        = (const float*)d_in[0];
  const float* noise    = (const float*)d_in[1];
  const float* gate_w   = (const float*)d_in[2];
  const float* fg_w1    = (const float*)d_in[3];
  const float* fg_b1    = (const float*)d_in[4];
  const float* fg_w2    = (const float*)d_in[5];
  const float* proj0    = (const float*)d_in[6];
  const float* proj1    = (const float*)d_in[7];
  const float* proj2    = (const float*)d_in[8];
  const float* hg_gain  = (const float*)d_in[9];
  const float* hg_decay = (const float*)d_in[10];
  const float* hf_w1    = (const float*)d_in[11];
  const float* hf_b1    = (const float*)d_in[12];
  const float* hf_w2    = (const float*)d_in[13];
  const float* hf_b2    = (const float*)d_in[14];
  const float* lg_gain  = (const float*)d_in[15];
  const float* lg_decay = (const float*)d_in[16];
  const float* lf_w     = (const float*)d_in[17];
  const float* lf_b     = (const float*)d_in[18];
  float* out = (float*)d_out;

  // workspace (floats): X 17,039,360 | Y0 8,519,680 | Y2 8,519,680 | small tail.
  // A,G overlay X (X dead after both k_projfreq). bodies for e0/e2 live in place in Y0/Y2.
  float* ws = (float*)d_ws;
  float2* X = (float2*)ws;
  float*  A = ws;                       // 8,388,608 floats
  float*  G = ws + 8388608;             // 8,388,608 floats
  float*  Y0 = ws + 17039360;
  float*  Y2 = Y0 + 8519680;
  float*  xmean  = Y2 + 8519680;        // 1024
  float*  gates  = xmean + 1024;        // 64
  float*  gsum   = gates + 64;          // 16
  float*  part_w = gsum + 16;           // 32768

  const int BSTR_F = 65*128*2;          // freq-expert body stride (in-place over Y slot)
  const int BSTR_C = 16384;             // conv-expert body stride

  // routing
  k_mean   <<<1024, 256, 0, stream>>>(x, xmean);
  k_fft2fwd<<<1024, 256, 0, stream>>>(x, X, part_w);
  k_routing<<<1, 128, 0, stream>>>(xmean, part_w, noise, gate_w, fg_w1, fg_b1, fg_w2, gates, gsum);
  k_init_out<<<16384, 256, 0, stream>>>((const float4*)x, gsum, (float4*)out);

  // frequency-domain projections (X alive)
  k_projfreq<<<dim3(2,65,16), 256, 0, stream>>>(X, proj0 + 0*2048, (float2*)Y0, gates, 0, hg_gain, hg_decay, 3.0f);
  k_projfreq<<<dim3(2,65,16), 256, 0, stream>>>(X, proj0 + 2*2048, (float2*)Y2, gates, 2, lg_gain, lg_decay, 1.0f);

  // inverse FFTs (bodies in place in Y0/Y2); X dead from here
  k_ifft2<<<512, 256, 0, stream>>>((float2*)Y0, gates, 0);
  k_ifft2<<<512, 256, 0, stream>>>((float2*)Y2, gates, 2);

  // expert 0
  k_proj   <<<dim3(64,16), 256, 0, stream>>>(x, proj0 + 0*2048, proj1 + 0*2048, A, G, gates, 0, 0);
  k_combine<<<dim3(64,16), 256, 0, stream>>>(Y0, G, proj2 + 0*2048, out, gates, 0, BSTR_F);

  // expert 2
  k_proj   <<<dim3(64,16), 256, 0, stream>>>(x, proj0 + 2*2048, proj1 + 2*2048, A, G, gates, 2, 0);
  k_combine<<<dim3(64,16), 256, 0, stream>>>(Y2, G, proj2 + 2*2048, out, gates, 2, BSTR_F);

  // expert 1 (dw3 -> gelu -> dw3); body into Y0 region (stride 16384)
  k_proj   <<<dim3(64,16), 256, 0, stream>>>(x, proj0 + 1*2048, proj1 + 1*2048, A, G, gates, 1, 1);
  k_conv3  <<<dim3(8,512), 256, 0, stream>>>(A, Y0, hf_w1, hf_b1, hf_w2, hf_b2, gates);
  k_combine<<<dim3(64,16), 256, 0, stream>>>(Y0, G, proj2 + 1*2048, out, gates, 1, BSTR_C);

  // expert 3 (dw7 -> gelu -> avgpool3)
  k_proj   <<<dim3(64,16), 256, 0, stream>>>(x, proj0 + 3*2048, proj1 + 3*2048, A, G, gates, 3, 1);
  k_conv7  <<<dim3(8,512), 256, 0, stream>>>(A, Y0, lf_w, lf_b, gates);
  k_combine<<<dim3(64,16), 256, 0, stream>>>(Y0, G, proj2 + 3*2048, out, gates, 3, BSTR_C);
}

// Round 3
// 692.671 us; speedup vs baseline: 1.3753x; 1.1788x over previous
//
#include <hip/hip_runtime.h>
#include <math.h>

// B=16, DIM=64, RANK=32, H=W=128, E=4, K=2, BINS=8, FREQ_DIM=64, KS=7
// Round 3: two-real-rows-per-complex-FFT packing (fwd+inv), 512-thread FFT blocks,
// xmean extracted from X[0][0]; proj/combine/projfreq use register accumulators +
// wave-uniform scalar weight loads (no LDS on the FMA path).

namespace {

struct cpx { float x, y; };
struct Tw7 { cpx t[7]; };

__device__ __forceinline__ cpx cmul(cpx a, cpx b){ return {a.x*b.x - a.y*b.y, a.x*b.y + a.y*b.x}; }

__device__ __forceinline__ cpx tw(int k, float invN){
  float s, c;
  sincosf(-6.283185307179586f * (float)k * invN, &s, &c);
  return {c, s};
}

__device__ __forceinline__ void init_tw(Tw7 &T, int lane){
  T.t[0] = tw(lane,      1.0f/128.0f);
  T.t[1] = tw(lane & 31, 1.0f/64.0f);
  T.t[2] = tw(lane & 15, 1.0f/32.0f);
  T.t[3] = tw(lane & 7,  1.0f/16.0f);
  T.t[4] = tw(lane & 3,  1.0f/8.0f);
  T.t[5] = tw(lane & 1,  1.0f/4.0f);
  T.t[6] = {1.0f, 0.0f};
}

__device__ __forceinline__ int br6(int l){ return (int)(__brev((unsigned)l) >> 26); }

// 128-pt DIF FFT across one wave: lane holds a=in[l], b=in[l+64].
// Output: a = F[2*br6(l)], b = F[2*br6(l)+1].
__device__ __forceinline__ void fft128(cpx &a, cpx &b, int lane, const Tw7 &T){
  cpx u{a.x + b.x, a.y + b.y};
  cpx v{a.x - b.x, a.y - b.y};
  v = cmul(v, T.t[0]);
  a = u; b = v;
  int s = 1;
  #pragma unroll
  for (int m = 32; m >= 1; m >>= 1, s++){
    float pax = __shfl_xor(a.x, m);
    float pay = __shfl_xor(a.y, m);
    float pbx = __shfl_xor(b.x, m);
    float pby = __shfl_xor(b.y, m);
    cpx w = T.t[s];
    if (lane & m){
      cpx ta{pax - a.x, pay - a.y};
      cpx tb{pbx - b.x, pby - b.y};
      a = cmul(ta, w);
      b = cmul(tb, w);
    } else {
      a.x += pax; a.y += pay;
      b.x += pbx; b.y += pby;
    }
  }
}

// X-spectrum layout (as round 2): row j (0..63, col0 packs Nyquist), col i.
#define LIDX(j,i) ((((j) << 7)) | (((i) ^ ((j) & 31)) & 127))
// Packed row-FFT storage: pair p (0..63), freq j (0..127).
#define ZIDX(p,j) ((((p) << 7)) | (((j) ^ (p)) & 127))

__device__ __forceinline__ float gelu_exact(float v){
  return 0.5f * v * (1.0f + erff(v * 0.70710678118654752f));
}

// ---------------- kernels ----------------

// Fused 2-D rFFT per (b,c) + radial energy partials + xmean. 512 threads.
__global__ __launch_bounds__(512) void k_fft2fwd(const float* __restrict__ x, float2* __restrict__ X,
                                                 float* __restrict__ part_w, float* __restrict__ xmean){
  __shared__ float re[8192];
  __shared__ float im[8192];
  int bc = blockIdx.x; int t = threadIdx.x;
  int lane = t & 63, wv = t >> 6;
  Tw7 T; init_tw(T, lane);
  const float* img = x + (size_t)bc * 16384;

  // row FFTs, two real rows packed per complex FFT: pair p -> rows 2p, 2p+1
  #pragma unroll 2
  for (int k = 0; k < 8; k++){
    int p = wv*8 + k;
    int h0 = 2*p, h1 = 2*p + 1;
    cpx a{img[h0*128 + lane],      img[h1*128 + lane]};
    cpx b{img[h0*128 + lane + 64], img[h1*128 + lane + 64]};
    fft128(a, b, lane, T);
    int j0 = 2*br6(lane), j1 = j0 + 1;
    re[ZIDX(p,j0)] = a.x; im[ZIDX(p,j0)] = a.y;
    re[ZIDX(p,j1)] = b.x; im[ZIDX(p,j1)] = b.y;
  }
  __syncthreads();

  // column FFTs: unpack two-rows trick on read; results staged in registers.
  float rax[8], ray[8], rbx[8], rby[8];
  #pragma unroll
  for (int k = 0; k < 8; k++){
    int jj = wv*8 + k;
    int p  = lane >> 1, s = lane & 1;
    int p2 = 32 + p;
    cpx a, b;
    if (jj == 0){
      a = { s ? im[ZIDX(p, 0)]  : re[ZIDX(p, 0)],
            s ? im[ZIDX(p, 64)] : re[ZIDX(p, 64)] };
      b = { s ? im[ZIDX(p2,0)]  : re[ZIDX(p2,0)],
            s ? im[ZIDX(p2,64)] : re[ZIDX(p2,64)] };
    } else {
      int jm = 128 - jj;
      float z1x = re[ZIDX(p,jj)],  z1y = im[ZIDX(p,jj)];
      float z2x = re[ZIDX(p,jm)],  z2y = im[ZIDX(p,jm)];
      if (s == 0) a = { 0.5f*(z1x + z2x), 0.5f*(z1y - z2y) };
      else        a = { 0.5f*(z1y + z2y), 0.5f*(z2x - z1x) };
      float w1x = re[ZIDX(p2,jj)], w1y = im[ZIDX(p2,jj)];
      float w2x = re[ZIDX(p2,jm)], w2y = im[ZIDX(p2,jm)];
      if (s == 0) b = { 0.5f*(w1x + w2x), 0.5f*(w1y - w2y) };
      else        b = { 0.5f*(w1y + w2y), 0.5f*(w2x - w1x) };
    }
    fft128(a, b, lane, T);
    rax[k] = a.x; ray[k] = a.y; rbx[k] = b.x; rby[k] = b.y;
  }
  __syncthreads();
  #pragma unroll
  for (int k = 0; k < 8; k++){
    int jj = wv*8 + k;
    int i0 = 2*br6(lane);
    re[LIDX(jj,i0)]   = rax[k]; im[LIDX(jj,i0)]   = ray[k];
    re[LIDX(jj,i0+1)] = rbx[k]; im[LIDX(jj,i0+1)] = rby[k];
  }
  __syncthreads();

  if (t == 0) xmean[bc] = re[LIDX(0,0)] * (1.0f/16384.0f);

  // radial energy
  float edges[9];
  float step = sqrtf(8192.0f) * 0.125f;
  #pragma unroll
  for (int k = 0; k <= 8; k++) edges[k] = step * (float)k;
  float acc[8] = {0,0,0,0,0,0,0,0};
  for (int idx = t; idx < 64*128; idx += 512){
    int j = idx >> 7, i = idx & 127;
    if (j == 0){
      float cr = re[LIDX(0,i)], ci = im[LIDX(0,i)];
      int in_ = (128 - i) & 127;
      float dr = re[LIDX(0,in_)], di = im[LIDX(0,in_)];
      float x0r = 0.5f*(cr + dr), x0i = 0.5f*(ci - di);
      float x6r = 0.5f*(ci + di), x6i = 0.5f*(dr - cr);
      float m0 = sqrtf(x0r*x0r + x0i*x0i) * (1.0f/16384.0f);
      float m6 = sqrtf(x6r*x6r + x6i*x6i) * (1.0f/16384.0f);
      float dyv = (float)(i - 64);
      float d0 = sqrtf(dyv*dyv + 4096.0f);
      float d6 = fabsf(dyv);
      #pragma unroll
      for (int k = 0; k < 8; k++){
        if (d0 >= edges[k] && d0 < edges[k+1]) acc[k] += m0;
        if (d6 >= edges[k] && d6 < edges[k+1]) acc[k] += m6;
      }
    } else {
      float zr = re[LIDX(j,i)], zi = im[LIDX(j,i)];
      float mag = sqrtf(zr*zr + zi*zi) * (2.0f/16384.0f);
      float dy = (float)(i - 64), dx = (float)(j - 64);
      float d = sqrtf(dy*dy + dx*dx);
      #pragma unroll
      for (int k = 0; k < 8; k++)
        if (d >= edges[k] && d < edges[k+1]) acc[k] += mag;
    }
  }
  #pragma unroll
  for (int k = 0; k < 8; k++){
    float v = acc[k];
    for (int off = 32; off > 0; off >>= 1) v += __shfl_xor(v, off);
    if (lane == 0) part_w[(bc*8 + wv)*8 + k] = v;
  }

  // coalesced X write-out
  float2* Xo = X + (size_t)bc * (65*128);
  for (int idx = t; idx < 65*128; idx += 512){
    int j = idx >> 7, i = idx & 127;
    float2 v;
    if (j == 0){
      float cr = re[LIDX(0,i)], ci = im[LIDX(0,i)];
      int in_ = (128 - i) & 127;
      float dr = re[LIDX(0,in_)], di = im[LIDX(0,in_)];
      v = make_float2(0.5f*(cr + dr), 0.5f*(ci - di));
    } else if (j == 64){
      float cr = re[LIDX(0,i)], ci = im[LIDX(0,i)];
      int in_ = (128 - i) & 127;
      float dr = re[LIDX(0,in_)], di = im[LIDX(0,in_)];
      v = make_float2(0.5f*(ci + di), 0.5f*(dr - cr));
    } else {
      v = make_float2(re[LIDX(j,i)], im[LIDX(j,i)]);
    }
    Xo[idx] = v;
  }
}

__global__ __launch_bounds__(128) void k_routing(const float* __restrict__ xmean, const float* __restrict__ part_w,
    const float* __restrict__ noise, const float* __restrict__ gate_w,
    const float* __restrict__ fg_w1, const float* __restrict__ fg_b1, const float* __restrict__ fg_w2,
    float* __restrict__ gates, float* __restrict__ gsum){
  __shared__ float femb[16][8];
  __shared__ float hid[16][64];
  __shared__ float lgt[16][4];
  int t = threadIdx.x;
  {
    int b = t >> 3, k = t & 7;
    float s = 0.f;
    for (int c = 0; c < 64; c++)
      for (int w = 0; w < 8; w++)
        s += part_w[((b*64 + c)*8 + w)*8 + k];
    femb[b][k] = s * (1.0f/64.0f);
  }
  __syncthreads();
  for (int idx = t; idx < 16*64; idx += 128){
    int b = idx >> 6, f = idx & 63;
    float s = fg_b1[f];
    for (int k = 0; k < 8; k++) s += femb[b][k] * fg_w1[f*8 + k];
    hid[b][f] = fmaxf(s, 0.f);
  }
  __syncthreads();
  if (t < 64){
    int b = t >> 2, e = t & 3;
    float s = 0.f;
    for (int c = 0; c < 64; c++) s += xmean[b*64 + c] * gate_w[e*64 + c];
    for (int f = 0; f < 64; f++) s += hid[b][f] * fg_w2[e*64 + f];
    lgt[b][e] = s + noise[b*4 + e] * 0.25f;
  }
  __syncthreads();
  if (t < 16){
    int b = t;
    float m = fmaxf(fmaxf(lgt[b][0], lgt[b][1]), fmaxf(lgt[b][2], lgt[b][3]));
    float p[4]; float sum = 0.f;
    for (int e = 0; e < 4; e++){ p[e] = expf(lgt[b][e] - m); sum += p[e]; }
    for (int e = 0; e < 4; e++) p[e] /= sum;
    int i1 = 0;
    for (int e = 1; e < 4; e++) if (p[e] > p[i1]) i1 = e;
    int i2 = -1;
    for (int e = 0; e < 4; e++){ if (e == i1) continue; if (i2 < 0 || p[e] > p[i2]) i2 = e; }
    for (int e = 0; e < 4; e++) gates[b*4 + e] = (e == i1 || e == i2) ? p[e] : 0.f;
    gsum[b] = p[i1] + p[i2];
  }
}

__global__ __launch_bounds__(256) void k_init_out(const float4* __restrict__ x4, const float* __restrict__ gsum,
    float4* __restrict__ out4){
  int i = blockIdx.x * 256 + threadIdx.x;
  int b = i >> 18;
  float g = gsum[b];
  float4 v = x4[i];
  out4[i] = make_float4(v.x*g, v.y*g, v.z*g, v.w*g);
}

// Y[b][r][j][i] = filt(i,j)/16384 * sum_c P0[r,c] X[b][c][j][i]   (gated per b)
__global__ __launch_bounds__(256) void k_projfreq(const float2* __restrict__ X, const float* __restrict__ P0,
    float2* __restrict__ Y, const float* __restrict__ gates, int e,
    const float* __restrict__ gainp, const float* __restrict__ decayp, float cmax){
  int b = blockIdx.z;
  if (gates[b*4 + e] == 0.f) return;
  int j = blockIdx.y;
  int i0 = blockIdx.x * 64;
  int t = threadIdx.x;
  __shared__ float2 sx[64][64];
  for (int idx = t; idx < 4096; idx += 256){
    int c = idx >> 6, ii = idx & 63;
    sx[c][ii] = X[(((size_t)(b*64 + c))*65 + j)*128 + i0 + ii];
  }
  __syncthreads();
  int ii = t & 63;
  int rg = __builtin_amdgcn_readfirstlane(t >> 6);
  int i = i0 + ii;
  float gain = *gainp, decay = *decayp;
  float fy = (float)(i < 64 ? i : i - 128) * (1.0f/128.0f);
  float fx = (float)j * (1.0f/128.0f);
  float fg = sqrtf(fy*fy + fx*fx);
  float filt = (1.0f - expf(-gain*fg)) * expf(-decay*fg);
  filt = fminf(fmaxf(filt, 0.0f), cmax) * (1.0f/16384.0f);
  float ax[8] = {0,0,0,0,0,0,0,0};
  float ay[8] = {0,0,0,0,0,0,0,0};
  const float* W = P0 + rg*8*64;
  for (int c = 0; c < 64; c++){
    float2 xv = sx[c][ii];
    #pragma unroll
    for (int r8 = 0; r8 < 8; r8++){
      float wv = W[r8*64 + c];          // wave-uniform -> s_load
      ax[r8] += wv * xv.x;
      ay[r8] += wv * xv.y;
    }
  }
  #pragma unroll
  for (int r8 = 0; r8 < 8; r8++){
    int r = rg*8 + r8;
    Y[(((size_t)(b*32 + r))*65 + j)*128 + i] = make_float2(ax[r8]*filt, ay[r8]*filt);
  }
}

// Fused inverse 2-D FFT per (b,r); body written IN PLACE over the Y slot. 512 threads.
__global__ __launch_bounds__(512) void k_ifft2(float2* __restrict__ Y, const float* __restrict__ gates, int e){
  int br_ = blockIdx.x; int b = br_ >> 5;
  if (gates[b*4 + e] == 0.f) return;
  __shared__ float re[8192];
  __shared__ float im[8192];
  int t = threadIdx.x; int lane = t & 63, wv = t >> 6;
  Tw7 T; init_tw(T, lane);
  float2* Yb = Y + (size_t)br_ * (65*128);

  // load; row 0 packed: P[i] = Y[0][i] + i*Y[64][i]
  for (int idx = t; idx < 64*128; idx += 512){
    int j = idx >> 7, i = idx & 127;
    if (j == 0){
      float2 y0 = Yb[i];
      float2 y6 = Yb[64*128 + i];
      re[LIDX(0,i)] = y0.x - y6.y;
      im[LIDX(0,i)] = y0.y + y6.x;
    } else {
      float2 v = Yb[j*128 + i];
      re[LIDX(j,i)] = v.x;
      im[LIDX(j,i)] = v.y;
    }
  }
  __syncthreads();

  // inverse column FFTs (unnormalized), in place per column
  #pragma unroll
  for (int k = 0; k < 8; k++){
    int jj = wv*8 + k;
    cpx a{re[LIDX(jj,lane)],    -im[LIDX(jj,lane)]};
    cpx b{re[LIDX(jj,lane+64)], -im[LIDX(jj,lane+64)]};
    fft128(a, b, lane, T);
    int i0 = 2*br6(lane);
    re[LIDX(jj,i0)]   = a.x; im[LIDX(jj,i0)]   = -a.y;
    re[LIDX(jj,i0+1)] = b.x; im[LIDX(jj,i0+1)] = -b.y;
  }
  __syncthreads();

  // inverse row transform: two real output rows per complex inverse FFT
  float* body = (float*)Yb;
  #pragma unroll 2
  for (int k = 0; k < 8; k++){
    int p = wv*8 + k;
    int h = 2*p, h1 = 2*p + 1;
    cpx a, b;
    if (lane == 0){
      a = { re[LIDX(0,h)], re[LIDX(0,h1)] };
      b = { im[LIDX(0,h)], im[LIDX(0,h1)] };
    } else {
      float yhr = re[LIDX(lane,h)],  yhi = im[LIDX(lane,h)];
      float y1r = re[LIDX(lane,h1)], y1i = im[LIDX(lane,h1)];
      a = { yhr - y1i, yhi + y1r };
      int lm = 64 - lane;
      float zhr = re[LIDX(lm,h)],  zhi = im[LIDX(lm,h)];
      float z1r = re[LIDX(lm,h1)], z1i = im[LIDX(lm,h1)];
      b = { zhr + z1i, z1r - zhi };
    }
    a.y = -a.y; b.y = -b.y;        // conj
    fft128(a, b, lane, T);
    int n0 = 2*br6(lane);
    body[h*128 + n0]      = a.x;   // conj on output: real part
    body[h1*128 + n0]     = -a.y;
    body[h*128 + n0 + 1]  = b.x;
    body[h1*128 + n0 + 1] = -b.y;
  }
}

// A = P0 x (if DOA), G = silu(P1 x); gated per b. x held in registers, weights scalar.
template<int DOA>
__global__ __launch_bounds__(256) void k_proj(const float* __restrict__ x, const float* __restrict__ P0,
    const float* __restrict__ P1, float* __restrict__ A, float* __restrict__ G,
    const float* __restrict__ gates, int e){
  int b = blockIdx.y;
  if (gates[b*4 + e] == 0.f) return;
  int hw = blockIdx.x * 256 + threadIdx.x;
  const float* xb = x + ((size_t)b*64)*16384 + hw;
  float xv[64];
  #pragma unroll
  for (int c = 0; c < 64; c++) xv[c] = xb[(size_t)c*16384];
  for (int r = 0; r < 32; r++){
    const float* w1r = P1 + r*64;
    float a1 = 0.f;
    #pragma unroll
    for (int c = 0; c < 64; c++) a1 += w1r[c] * xv[c];
    size_t o = ((size_t)(b*32 + r))*16384 + hw;
    if (DOA){
      const float* w0r = P0 + r*64;
      float a0 = 0.f;
      #pragma unroll
      for (int c = 0; c < 64; c++) a0 += w0r[c] * xv[c];
      A[o] = a0;
    }
    G[o] = a1 / (1.0f + expf(-a1));
  }
}

// Expert 1 fused: dw3 -> gelu -> dw3, LDS-tiled (16 out rows x 128)
__global__ __launch_bounds__(256) void k_conv3(const float* __restrict__ A, float* __restrict__ body,
    const float* __restrict__ w1g, const float* __restrict__ b1g,
    const float* __restrict__ w2g, const float* __restrict__ b2g,
    const float* __restrict__ gates){
  int br_ = blockIdx.y; int b = br_ >> 5, r = br_ & 31;
  if (gates[b*4 + 1] == 0.f) return;
  int h0 = blockIdx.x * 16;
  int t = threadIdx.x;
  __shared__ float sin_[20*130];
  __shared__ float st[18*130];
  for (int i = t; i < 20*130; i += 256) sin_[i] = 0.f;
  for (int i = t; i < 18*130; i += 256) st[i] = 0.f;
  float w1[9], w2[9];
  #pragma unroll
  for (int k = 0; k < 9; k++){ w1[k] = w1g[r*9 + k]; w2[k] = w2g[r*9 + k]; }
  float b1 = b1g[r], b2 = b2g[r];
  __syncthreads();
  const float* ip = A + ((size_t)br_ << 14);
  for (int idx = t; idx < 20*128; idx += 256){
    int li = idx >> 7, ww = idx & 127;
    int ih = h0 - 2 + li;
    if (ih >= 0 && ih < 128) sin_[li*130 + 1 + ww] = ip[ih*128 + ww];
  }
  __syncthreads();
  for (int idx = t; idx < 18*128; idx += 256){
    int li = idx >> 7, ww = idx & 127;
    int hs = h0 - 1 + li;
    if (hs >= 0 && hs < 128){
      float acc = b1;
      #pragma unroll
      for (int kh = 0; kh < 3; kh++)
        #pragma unroll
        for (int kw = 0; kw < 3; kw++)
          acc += w1[kh*3 + kw] * sin_[(li + kh)*130 + ww + kw];
      st[li*130 + 1 + ww] = gelu_exact(acc);
    }
  }
  __syncthreads();
  float* op = body + ((size_t)br_ << 14);
  for (int idx = t; idx < 16*128; idx += 256){
    int li = idx >> 7, ww = idx & 127;
    int ho = h0 + li;
    float acc = b2;
    #pragma unroll
    for (int kh = 0; kh < 3; kh++)
      #pragma unroll
      for (int kw = 0; kw < 3; kw++)
        acc += w2[kh*3 + kw] * st[(li + kh)*130 + ww + kw];
    op[ho*128 + ww] = acc;
  }
}

// Expert 3 fused: dw7 -> gelu -> avgpool3 (count_include_pad)
__global__ __launch_bounds__(256) void k_conv7(const float* __restrict__ A, float* __restrict__ body,
    const float* __restrict__ wg, const float* __restrict__ bg,
    const float* __restrict__ gates){
  int br_ = blockIdx.y; int b = br_ >> 5, r = br_ & 31;
  if (gates[b*4 + 3] == 0.f) return;
  int h0 = blockIdx.x * 16;
  int t = threadIdx.x;
  __shared__ float sin_[24*134];
  __shared__ float st[18*134];
  __shared__ float wsh[49];
  for (int i = t; i < 24*134; i += 256) sin_[i] = 0.f;
  for (int i = t; i < 18*134; i += 256) st[i] = 0.f;
  if (t < 49) wsh[t] = wg[r*49 + t];
  float bias = bg[r];
  __syncthreads();
  const float* ip = A + ((size_t)br_ << 14);
  for (int idx = t; idx < 24*128; idx += 256){
    int li = idx >> 7, ww = idx & 127;
    int ih = h0 - 4 + li;
    if (ih >= 0 && ih < 128) sin_[li*134 + 3 + ww] = ip[ih*128 + ww];
  }
  __syncthreads();
  for (int idx = t; idx < 18*128; idx += 256){
    int li = idx >> 7, ww = idx & 127;
    int hs = h0 - 1 + li;
    if (hs >= 0 && hs < 128){
      float acc = bias;
      #pragma unroll
      for (int kh = 0; kh < 7; kh++)
        #pragma unroll
        for (int kw = 0; kw < 7; kw++)
          acc += wsh[kh*7 + kw] * sin_[(li + kh)*134 + ww + kw];
      st[li*134 + 1 + ww] = gelu_exact(acc);
    }
  }
  __syncthreads();
  float* op = body + ((size_t)br_ << 14);
  for (int idx = t; idx < 16*128; idx += 256){
    int li = idx >> 7, ww = idx & 127;
    int ho = h0 + li;
    float acc = 0.f;
    #pragma unroll
    for (int kh = 0; kh < 3; kh++)
      #pragma unroll
      for (int kw = 0; kw < 3; kw++)
        acc += st[(li + kh)*134 + ww + kw];
    op[ho*128 + ww] = acc * (1.0f/9.0f);
  }
}

// out[b,c,:] += gate * sum_r P2[c,r] * (body[b,r,:] * G[b,r,:]); register v, scalar weights
__global__ __launch_bounds__(256) void k_combine(const float* __restrict__ body, const float* __restrict__ G,
    const float* __restrict__ P2, float* __restrict__ out, const float* __restrict__ gates, int e, int bstride){
  int b = blockIdx.y;
  float gv = gates[b*4 + e];
  if (gv == 0.f) return;
  int hw = blockIdx.x * 256 + threadIdx.x;
  float v[32];
  #pragma unroll
  for (int r = 0; r < 32; r++)
    v[r] = body[((size_t)(b*32 + r))*bstride + hw] * G[((size_t)(b*32 + r))*16384 + hw];
  #pragma unroll 4
  for (int c = 0; c < 64; c++){
    const float* wc = P2 + c*32;
    float acc = 0.f;
    #pragma unroll
    for (int r = 0; r < 32; r++) acc += wc[r] * v[r];
    size_t o = ((size_t)(b*64 + c))*16384 + hw;
    out[o] += gv * acc;
  }
}

} // namespace

extern "C" void kernel_launch(void* const* d_in, const int* in_sizes, int n_in,
                              void* d_out, int out_size, void* d_ws, size_t ws_size,
                              hipStream_t stream) {
  (void)in_sizes; (void)n_in; (void)out_size; (void)ws_size;
  const float* x        = (const float*)d_in[0];
  const float* noise    = (const float*)d_in[1];
  const float* gate_w   = (const float*)d_in[2];
  const float* fg_w1    = (const float*)d_in[3];
  const float* fg_b1    = (const float*)d_in[4];
  const float* fg_w2    = (const float*)d_in[5];
  const float* proj0    = (const float*)d_in[6];
  const float* proj1    = (const float*)d_in[7];
  const float* proj2    = (const float*)d_in[8];
  const float* hg_gain  = (const float*)d_in[9];
  const float* hg_decay = (const float*)d_in[10];
  const float* hf_w1    = (const float*)d_in[11];
  const float* hf_b1    = (const float*)d_in[12];
  const float* hf_w2    = (const float*)d_in[13];
  const float* hf_b2    = (const float*)d_in[14];
  const float* lg_gain  = (const float*)d_in[15];
  const float* lg_decay = (const float*)d_in[16];
  const float* lf_w     = (const float*)d_in[17];
  const float* lf_b     = (const float*)d_in[18];
  float* out = (float*)d_out;

  float* ws = (float*)d_ws;
  float2* X = (float2*)ws;              // [1024][65][128] float2
  float*  A = ws;                       // overlays X (X dead after projfreq)
  float*  G = ws + 8388608;
  float*  Y0 = ws + 17039360;
  float*  Y2 = Y0 + 8519680;
  float*  xmean  = Y2 + 8519680;        // 1024
  float*  gates  = xmean + 1024;        // 64
  float*  gsum   = gates + 64;          // 16
  float*  part_w = gsum + 16;           // 65536

  const int BSTR_F = 65*128*2;
  const int BSTR_C = 16384;

  // routing (xmean comes from X[0][0])
  k_fft2fwd<<<1024, 512, 0, stream>>>(x, X, part_w, xmean);
  k_routing<<<1, 128, 0, stream>>>(xmean, part_w, noise, gate_w, fg_w1, fg_b1, fg_w2, gates, gsum);
  k_init_out<<<16384, 256, 0, stream>>>((const float4*)x, gsum, (float4*)out);

  // frequency-domain projections (X alive)
  k_projfreq<<<dim3(2,65,16), 256, 0, stream>>>(X, proj0 + 0*2048, (float2*)Y0, gates, 0, hg_gain, hg_decay, 3.0f);
  k_projfreq<<<dim3(2,65,16), 256, 0, stream>>>(X, proj0 + 2*2048, (float2*)Y2, gates, 2, lg_gain, lg_decay, 1.0f);

  // inverse FFTs (bodies in place in Y0/Y2); X dead from here
  k_ifft2<<<512, 512, 0, stream>>>((float2*)Y0, gates, 0);
  k_ifft2<<<512, 512, 0, stream>>>((float2*)Y2, gates, 2);

  // expert 0
  k_proj<0><<<dim3(64,16), 256, 0, stream>>>(x, proj0 + 0*2048, proj1 + 0*2048, A, G, gates, 0);
  k_combine<<<dim3(64,16), 256, 0, stream>>>(Y0, G, proj2 + 0*2048, out, gates, 0, BSTR_F);

  // expert 2
  k_proj<0><<<dim3(64,16), 256, 0, stream>>>(x, proj0 + 2*2048, proj1 + 2*2048, A, G, gates, 2);
  k_combine<<<dim3(64,16), 256, 0, stream>>>(Y2, G, proj2 + 2*2048, out, gates, 2, BSTR_F);

  // expert 1 (dw3 -> gelu -> dw3)
  k_proj<1><<<dim3(64,16), 256, 0, stream>>>(x, proj0 + 1*2048, proj1 + 1*2048, A, G, gates, 1);
  k_conv3<<<dim3(8,512), 256, 0, stream>>>(A, Y0, hf_w1, hf_b1, hf_w2, hf_b2, gates);
  k_combine<<<dim3(64,16), 256, 0, stream>>>(Y0, G, proj2 + 1*2048, out, gates, 1, BSTR_C);

  // expert 3 (dw7 -> gelu -> avgpool3)
  k_proj<1><<<dim3(64,16), 256, 0, stream>>>(x, proj0 + 3*2048, proj1 + 3*2048, A, G, gates, 3);
  k_conv7<<<dim3(8,512), 256, 0, stream>>>(A, Y0, lf_w, lf_b, gates);
  k_combine<<<dim3(64,16), 256, 0, stream>>>(Y0, G, proj2 + 3*2048, out, gates, 3, BSTR_C);
}

// Round 4
// 469.508 us; speedup vs baseline: 2.0289x; 1.4753x over previous
//
#include <hip/hip_runtime.h>
#include <math.h>

// B=16, DIM=64, RANK=32, H=W=128, E=4, K=2, BINS=8, FREQ_DIM=64, KS=7
// Round 4: slot-based restructure (every b has exactly 2 active experts).
// 9 launches. G recomputed in combine (no G buffer). float2 LDS in FFT kernels.

namespace {

struct cpx { float x, y; };
struct Tw7 { cpx t[7]; };

__device__ __forceinline__ cpx cmul(cpx a, cpx b){ return {a.x*b.x - a.y*b.y, a.x*b.y + a.y*b.x}; }

__device__ __forceinline__ cpx tw(int k, float invN){
  float s, c;
  sincosf(-6.283185307179586f * (float)k * invN, &s, &c);
  return {c, s};
}

__device__ __forceinline__ void init_tw(Tw7 &T, int lane){
  T.t[0] = tw(lane,      1.0f/128.0f);
  T.t[1] = tw(lane & 31, 1.0f/64.0f);
  T.t[2] = tw(lane & 15, 1.0f/32.0f);
  T.t[3] = tw(lane & 7,  1.0f/16.0f);
  T.t[4] = tw(lane & 3,  1.0f/8.0f);
  T.t[5] = tw(lane & 1,  1.0f/4.0f);
  T.t[6] = {1.0f, 0.0f};
}

__device__ __forceinline__ int br6(int l){ return (int)(__brev((unsigned)l) >> 26); }

// 128-pt DIF FFT across one wave: lane holds a=in[l], b=in[l+64].
// Output: a = F[2*br6(l)], b = F[2*br6(l)+1].
__device__ __forceinline__ void fft128(cpx &a, cpx &b, int lane, const Tw7 &T){
  cpx u{a.x + b.x, a.y + b.y};
  cpx v{a.x - b.x, a.y - b.y};
  v = cmul(v, T.t[0]);
  a = u; b = v;
  int s = 1;
  #pragma unroll
  for (int m = 32; m >= 1; m >>= 1, s++){
    float pax = __shfl_xor(a.x, m);
    float pay = __shfl_xor(a.y, m);
    float pbx = __shfl_xor(b.x, m);
    float pby = __shfl_xor(b.y, m);
    cpx w = T.t[s];
    if (lane & m){
      cpx ta{pax - a.x, pay - a.y};
      cpx tb{pbx - b.x, pby - b.y};
      a = cmul(ta, w);
      b = cmul(tb, w);
    } else {
      a.x += pax; a.y += pay;
      b.x += pbx; b.y += pby;
    }
  }
}

// spectrum layout: row j (0..63, col0 packs Nyquist), col i. float2 elements.
#define LIDX(j,i) ((((j) << 7)) | (((i) ^ ((j) & 31)) & 127))
// packed row-FFT storage: pair p (0..63), freq j (0..127)
#define ZIDX(p,j) ((((p) << 7)) | (((j) ^ (p)) & 127))

__device__ __forceinline__ float gelu_exact(float v){
  return 0.5f * v * (1.0f + erff(v * 0.70710678118654752f));
}

__device__ __forceinline__ float silu(float v){
  return v / (1.0f + expf(-v));
}

// ---------------- kernels ----------------

// Fused 2-D rFFT per (b,c) + radial energy partials + xmean. 512 threads.
__global__ __launch_bounds__(512) void k_fft2fwd(const float* __restrict__ x, float2* __restrict__ X,
                                                 float* __restrict__ part_w, float* __restrict__ xmean){
  __shared__ float2 z[8192];
  int bc = blockIdx.x; int t = threadIdx.x;
  int lane = t & 63, wv = t >> 6;
  Tw7 T; init_tw(T, lane);
  const float* img = x + (size_t)bc * 16384;

  // row FFTs, two real rows packed per complex FFT: pair p -> rows 2p, 2p+1
  #pragma unroll 4
  for (int k = 0; k < 8; k++){
    int p = wv*8 + k;
    int h0 = 2*p, h1 = 2*p + 1;
    cpx a{img[h0*128 + lane],      img[h1*128 + lane]};
    cpx b{img[h0*128 + lane + 64], img[h1*128 + lane + 64]};
    fft128(a, b, lane, T);
    int j0 = 2*br6(lane), j1 = j0 + 1;
    z[ZIDX(p,j0)] = make_float2(a.x, a.y);
    z[ZIDX(p,j1)] = make_float2(b.x, b.y);
  }
  __syncthreads();

  // column FFTs: unpack two-rows trick on read; results staged in registers.
  float rax[8], ray[8], rbx[8], rby[8];
  #pragma unroll
  for (int k = 0; k < 8; k++){
    int jj = wv*8 + k;
    int p  = lane >> 1, s = lane & 1;
    int p2 = 32 + p;
    cpx a, b;
    if (jj == 0){
      float2 z0 = z[ZIDX(p,0)],  z64 = z[ZIDX(p,64)];
      float2 w0 = z[ZIDX(p2,0)], w64 = z[ZIDX(p2,64)];
      a = { s ? z0.y : z0.x, s ? z64.y : z64.x };
      b = { s ? w0.y : w0.x, s ? w64.y : w64.x };
    } else {
      int jm = 128 - jj;
      float2 z1 = z[ZIDX(p,jj)],  z2 = z[ZIDX(p,jm)];
      if (s == 0) a = { 0.5f*(z1.x + z2.x), 0.5f*(z1.y - z2.y) };
      else        a = { 0.5f*(z1.y + z2.y), 0.5f*(z2.x - z1.x) };
      float2 w1 = z[ZIDX(p2,jj)], w2 = z[ZIDX(p2,jm)];
      if (s == 0) b = { 0.5f*(w1.x + w2.x), 0.5f*(w1.y - w2.y) };
      else        b = { 0.5f*(w1.y + w2.y), 0.5f*(w2.x - w1.x) };
    }
    fft128(a, b, lane, T);
    rax[k] = a.x; ray[k] = a.y; rbx[k] = b.x; rby[k] = b.y;
  }
  __syncthreads();
  #pragma unroll
  for (int k = 0; k < 8; k++){
    int jj = wv*8 + k;
    int i0 = 2*br6(lane);
    z[LIDX(jj,i0)]   = make_float2(rax[k], ray[k]);
    z[LIDX(jj,i0+1)] = make_float2(rbx[k], rby[k]);
  }
  __syncthreads();

  if (t == 0) xmean[bc] = z[LIDX(0,0)].x * (1.0f/16384.0f);

  // radial energy
  float edges[9];
  float step = sqrtf(8192.0f) * 0.125f;
  #pragma unroll
  for (int k = 0; k <= 8; k++) edges[k] = step * (float)k;
  float acc[8] = {0,0,0,0,0,0,0,0};
  for (int idx = t; idx < 64*128; idx += 512){
    int j = idx >> 7, i = idx & 127;
    if (j == 0){
      float2 c0 = z[LIDX(0,i)];
      int in_ = (128 - i) & 127;
      float2 d0v = z[LIDX(0,in_)];
      float x0r = 0.5f*(c0.x + d0v.x), x0i = 0.5f*(c0.y - d0v.y);
      float x6r = 0.5f*(c0.y + d0v.y), x6i = 0.5f*(d0v.x - c0.x);
      float m0 = sqrtf(x0r*x0r + x0i*x0i) * (1.0f/16384.0f);
      float m6 = sqrtf(x6r*x6r + x6i*x6i) * (1.0f/16384.0f);
      float dyv = (float)(i - 64);
      float d0 = sqrtf(dyv*dyv + 4096.0f);
      float d6 = fabsf(dyv);
      #pragma unroll
      for (int k = 0; k < 8; k++){
        if (d0 >= edges[k] && d0 < edges[k+1]) acc[k] += m0;
        if (d6 >= edges[k] && d6 < edges[k+1]) acc[k] += m6;
      }
    } else {
      float2 zv = z[LIDX(j,i)];
      float mag = sqrtf(zv.x*zv.x + zv.y*zv.y) * (2.0f/16384.0f);
      float dy = (float)(i - 64), dx = (float)(j - 64);
      float d = sqrtf(dy*dy + dx*dx);
      #pragma unroll
      for (int k = 0; k < 8; k++)
        if (d >= edges[k] && d < edges[k+1]) acc[k] += mag;
    }
  }
  #pragma unroll
  for (int k = 0; k < 8; k++){
    float v = acc[k];
    for (int off = 32; off > 0; off >>= 1) v += __shfl_xor(v, off);
    if (lane == 0) part_w[(bc*8 + wv)*8 + k] = v;
  }

  // coalesced X write-out
  float2* Xo = X + (size_t)bc * (65*128);
  for (int idx = t; idx < 65*128; idx += 512){
    int j = idx >> 7, i = idx & 127;
    float2 v;
    if (j == 0){
      float2 c0 = z[LIDX(0,i)];
      int in_ = (128 - i) & 127;
      float2 d0v = z[LIDX(0,in_)];
      v = make_float2(0.5f*(c0.x + d0v.x), 0.5f*(c0.y - d0v.y));
    } else if (j == 64){
      float2 c0 = z[LIDX(0,i)];
      int in_ = (128 - i) & 127;
      float2 d0v = z[LIDX(0,in_)];
      v = make_float2(0.5f*(c0.y + d0v.y), 0.5f*(d0v.x - c0.x));
    } else {
      v = z[LIDX(j,i)];
    }
    Xo[idx] = v;
  }
}

__global__ __launch_bounds__(128) void k_routing(const float* __restrict__ xmean, const float* __restrict__ part_w,
    const float* __restrict__ noise, const float* __restrict__ gate_w,
    const float* __restrict__ fg_w1, const float* __restrict__ fg_b1, const float* __restrict__ fg_w2,
    int* __restrict__ slot_e, int* __restrict__ slot_of, float* __restrict__ slot_g){
  __shared__ float femb[16][8];
  __shared__ float hid[16][64];
  __shared__ float lgt[16][4];
  int t = threadIdx.x;
  {
    int b = t >> 3, k = t & 7;
    float s = 0.f;
    for (int c = 0; c < 64; c++)
      for (int w = 0; w < 8; w++)
        s += part_w[((b*64 + c)*8 + w)*8 + k];
    femb[b][k] = s * (1.0f/64.0f);
  }
  __syncthreads();
  for (int idx = t; idx < 16*64; idx += 128){
    int b = idx >> 6, f = idx & 63;
    float s = fg_b1[f];
    for (int k = 0; k < 8; k++) s += femb[b][k] * fg_w1[f*8 + k];
    hid[b][f] = fmaxf(s, 0.f);
  }
  __syncthreads();
  if (t < 64){
    int b = t >> 2, e = t & 3;
    float s = 0.f;
    for (int c = 0; c < 64; c++) s += xmean[b*64 + c] * gate_w[e*64 + c];
    for (int f = 0; f < 64; f++) s += hid[b][f] * fg_w2[e*64 + f];
    lgt[b][e] = s + noise[b*4 + e] * 0.25f;   // NOISE_STD = 1/E
  }
  __syncthreads();
  if (t < 16){
    int b = t;
    float m = fmaxf(fmaxf(lgt[b][0], lgt[b][1]), fmaxf(lgt[b][2], lgt[b][3]));
    float p[4]; float sum = 0.f;
    for (int e = 0; e < 4; e++){ p[e] = expf(lgt[b][e] - m); sum += p[e]; }
    for (int e = 0; e < 4; e++) p[e] /= sum;
    int i1 = 0;
    for (int e = 1; e < 4; e++) if (p[e] > p[i1]) i1 = e;   // ties -> lowest idx (lax.top_k)
    int i2 = -1;
    for (int e = 0; e < 4; e++){ if (e == i1) continue; if (i2 < 0 || p[e] > p[i2]) i2 = e; }
    slot_e[b*2 + 0] = i1;
    slot_e[b*2 + 1] = i2;
    slot_g[b*2 + 0] = p[i1];
    slot_g[b*2 + 1] = p[i2];
    for (int e = 0; e < 4; e++) slot_of[b*4 + e] = (e == i1) ? 0 : ((e == i2) ? 1 : -1);
  }
}

// Yspec[bs][r][j][i] = filt(i,j)/16384 * sum_c P0[r,c] X[b][c][j][i]; bs = b*2+slot
__global__ __launch_bounds__(256) void k_projfreq(const float2* __restrict__ X, const float* __restrict__ P0,
    float2* __restrict__ Y, const int* __restrict__ slot_of, int e,
    const float* __restrict__ gainp, const float* __restrict__ decayp, float cmax){
  int b = blockIdx.z;
  int slot = slot_of[b*4 + e];
  if (slot < 0) return;
  int bs = b*2 + slot;
  int j = blockIdx.y;
  int i0 = blockIdx.x * 64;
  int t = threadIdx.x;
  __shared__ float2 sx[64][64];
  for (int idx = t; idx < 4096; idx += 256){
    int c = idx >> 6, ii = idx & 63;
    sx[c][ii] = X[(((size_t)(b*64 + c))*65 + j)*128 + i0 + ii];
  }
  __syncthreads();
  int ii = t & 63;
  int rg = __builtin_amdgcn_readfirstlane(t >> 6);
  int i = i0 + ii;
  float gain = *gainp, decay = *decayp;
  float fy = (float)(i < 64 ? i : i - 128) * (1.0f/128.0f);
  float fx = (float)j * (1.0f/128.0f);
  float fg = sqrtf(fy*fy + fx*fx);
  float filt = (1.0f - expf(-gain*fg)) * expf(-decay*fg);
  filt = fminf(fmaxf(filt, 0.0f), cmax) * (1.0f/16384.0f);
  float ax[8] = {0,0,0,0,0,0,0,0};
  float ay[8] = {0,0,0,0,0,0,0,0};
  const float* W = P0 + rg*8*64;
  for (int c = 0; c < 64; c++){
    float2 xv = sx[c][ii];
    #pragma unroll
    for (int r8 = 0; r8 < 8; r8++){
      float wv = W[r8*64 + c];          // wave-uniform -> s_load
      ax[r8] += wv * xv.x;
      ay[r8] += wv * xv.y;
    }
  }
  #pragma unroll
  for (int r8 = 0; r8 < 8; r8++){
    int r = rg*8 + r8;
    Y[((size_t)(bs*32 + r))*8320 + j*128 + i] = make_float2(ax[r8]*filt, ay[r8]*filt);
  }
}

// Fused inverse 2-D FFT per (bs,r) for freq slots; body written IN PLACE. 512 threads.
__global__ __launch_bounds__(512) void k_ifft2(float2* __restrict__ Y, const int* __restrict__ slot_e){
  int blk = blockIdx.x;
  int bs = blk >> 5, r = blk & 31;
  int es = slot_e[bs];
  if (es == 1 || es == 3) return;     // conv slots skip
  __shared__ float2 z[8192];
  int t = threadIdx.x; int lane = t & 63, wv = t >> 6;
  Tw7 T; init_tw(T, lane);
  float2* Yb = Y + (size_t)(bs*32 + r) * 8320;

  // load; row 0 packed: P[i] = Y[0][i] + i*Y[64][i]
  for (int idx = t; idx < 8192; idx += 512){
    int j = idx >> 7, i = idx & 127;
    if (j == 0){
      float2 y0 = Yb[i];
      float2 y6 = Yb[8192 + i];
      z[LIDX(0,i)] = make_float2(y0.x - y6.y, y0.y + y6.x);
    } else {
      z[LIDX(j,i)] = Yb[idx];
    }
  }
  __syncthreads();

  // inverse column FFTs (unnormalized), in place per column
  #pragma unroll
  for (int k = 0; k < 8; k++){
    int jj = wv*8 + k;
    float2 z0 = z[LIDX(jj,lane)], z1 = z[LIDX(jj,lane+64)];
    cpx a{z0.x, -z0.y}, b{z1.x, -z1.y};
    fft128(a, b, lane, T);
    int i0 = 2*br6(lane);
    z[LIDX(jj,i0)]   = make_float2(a.x, -a.y);
    z[LIDX(jj,i0+1)] = make_float2(b.x, -b.y);
  }
  __syncthreads();

  // inverse row transform: two real output rows per complex inverse FFT
  float* body = (float*)Yb;
  #pragma unroll 2
  for (int k = 0; k < 8; k++){
    int p = wv*8 + k;
    int h = 2*p, h1 = 2*p + 1;
    cpx a, b;
    if (lane == 0){
      float2 c0 = z[LIDX(0,h)], c1 = z[LIDX(0,h1)];
      a = { c0.x, c1.x };
      b = { c0.y, c1.y };
    } else {
      float2 yh = z[LIDX(lane,h)], y1 = z[LIDX(lane,h1)];
      a = { yh.x - y1.y, yh.y + y1.x };
      int lm = 64 - lane;
      float2 zh = z[LIDX(lm,h)], z1_ = z[LIDX(lm,h1)];
      b = { zh.x + z1_.y, z1_.x - zh.y };
    }
    a.y = -a.y; b.y = -b.y;        // conj
    fft128(a, b, lane, T);
    int n0 = 2*br6(lane);
    body[h*128 + n0]      = a.x;   // conj on output: real part
    body[h1*128 + n0]     = -a.y;
    body[h*128 + n0 + 1]  = b.x;
    body[h1*128 + n0 + 1] = -b.y;
  }
}

// A[bs][r] = P0[e_s] x[b]  for conv slots only.
__global__ __launch_bounds__(256) void k_projA(const float* __restrict__ x, const float* __restrict__ proj0,
    const int* __restrict__ slot_e, float* __restrict__ A){
  int b = blockIdx.y;
  int e0 = slot_e[b*2 + 0], e1 = slot_e[b*2 + 1];
  bool c0 = (e0 == 1) || (e0 == 3);
  bool c1 = (e1 == 1) || (e1 == 3);
  if (!c0 && !c1) return;
  int hw = blockIdx.x * 256 + threadIdx.x;
  const float* xb = x + (size_t)b*64*16384 + hw;
  float xv[64];
  #pragma unroll
  for (int c = 0; c < 64; c++) xv[c] = xb[(size_t)c*16384];
  if (c0){
    const float* W = proj0 + __builtin_amdgcn_readfirstlane(e0)*2048;
    float* Ab = A + (size_t)(b*2 + 0)*32*16384 + hw;
    for (int r = 0; r < 32; r++){
      float a = 0.f;
      #pragma unroll
      for (int c = 0; c < 64; c++) a += W[r*64 + c] * xv[c];
      Ab[(size_t)r*16384] = a;
    }
  }
  if (c1){
    const float* W = proj0 + __builtin_amdgcn_readfirstlane(e1)*2048;
    float* Ab = A + (size_t)(b*2 + 1)*32*16384 + hw;
    for (int r = 0; r < 32; r++){
      float a = 0.f;
      #pragma unroll
      for (int c = 0; c < 64; c++) a += W[r*64 + c] * xv[c];
      Ab[(size_t)r*16384] = a;
    }
  }
}

// Expert 1 fused: dw3 -> gelu -> dw3, LDS-tiled (16 out rows x 128)
__global__ __launch_bounds__(256) void k_conv3(const float* __restrict__ A, float* __restrict__ bodyY,
    const float* __restrict__ w1g, const float* __restrict__ b1g,
    const float* __restrict__ w2g, const float* __restrict__ b2g,
    const int* __restrict__ slot_of){
  int by = blockIdx.y; int b = by >> 5, r = by & 31;
  int slot = slot_of[b*4 + 1];
  if (slot < 0) return;
  int bs = b*2 + slot;
  int h0 = blockIdx.x * 16;
  int t = threadIdx.x;
  __shared__ float sin_[20*130];
  __shared__ float st[18*130];
  for (int i = t; i < 20*130; i += 256) sin_[i] = 0.f;
  for (int i = t; i < 18*130; i += 256) st[i] = 0.f;
  float w1[9], w2[9];
  #pragma unroll
  for (int k = 0; k < 9; k++){ w1[k] = w1g[r*9 + k]; w2[k] = w2g[r*9 + k]; }
  float b1 = b1g[r], b2 = b2g[r];
  __syncthreads();
  const float* ip = A + (size_t)(bs*32 + r)*16384;
  for (int idx = t; idx < 20*128; idx += 256){
    int li = idx >> 7, ww = idx & 127;
    int ih = h0 - 2 + li;
    if (ih >= 0 && ih < 128) sin_[li*130 + 1 + ww] = ip[ih*128 + ww];
  }
  __syncthreads();
  for (int idx = t; idx < 18*128; idx += 256){
    int li = idx >> 7, ww = idx & 127;
    int hs = h0 - 1 + li;
    if (hs >= 0 && hs < 128){
      float acc = b1;
      #pragma unroll
      for (int kh = 0; kh < 3; kh++)
        #pragma unroll
        for (int kw = 0; kw < 3; kw++)
          acc += w1[kh*3 + kw] * sin_[(li + kh)*130 + ww + kw];
      st[li*130 + 1 + ww] = gelu_exact(acc);
    }
  }
  __syncthreads();
  float* op = bodyY + (size_t)(bs*32 + r)*16640;
  for (int idx = t; idx < 16*128; idx += 256){
    int li = idx >> 7, ww = idx & 127;
    int ho = h0 + li;
    float acc = b2;
    #pragma unroll
    for (int kh = 0; kh < 3; kh++)
      #pragma unroll
      for (int kw = 0; kw < 3; kw++)
        acc += w2[kh*3 + kw] * st[(li + kh)*130 + ww + kw];
    op[ho*128 + ww] = acc;
  }
}

// Expert 3 fused: dw7 -> gelu -> avgpool3 (count_include_pad)
__global__ __launch_bounds__(256) void k_conv7(const float* __restrict__ A, float* __restrict__ bodyY,
    const float* __restrict__ wg, const float* __restrict__ bg,
    const int* __restrict__ slot_of){
  int by = blockIdx.y; int b = by >> 5, r = by & 31;
  int slot = slot_of[b*4 + 3];
  if (slot < 0) return;
  int bs = b*2 + slot;
  int h0 = blockIdx.x * 16;
  int t = threadIdx.x;
  __shared__ float sin_[24*134];
  __shared__ float st[18*134];
  __shared__ float wsh[49];
  for (int i = t; i < 24*134; i += 256) sin_[i] = 0.f;
  for (int i = t; i < 18*134; i += 256) st[i] = 0.f;
  if (t < 49) wsh[t] = wg[r*49 + t];
  float bias = bg[r];
  __syncthreads();
  const float* ip = A + (size_t)(bs*32 + r)*16384;
  for (int idx = t; idx < 24*128; idx += 256){
    int li = idx >> 7, ww = idx & 127;
    int ih = h0 - 4 + li;
    if (ih >= 0 && ih < 128) sin_[li*134 + 3 + ww] = ip[ih*128 + ww];
  }
  __syncthreads();
  for (int idx = t; idx < 18*128; idx += 256){
    int li = idx >> 7, ww = idx & 127;
    int hs = h0 - 1 + li;
    if (hs >= 0 && hs < 128){
      float acc = bias;
      #pragma unroll
      for (int kh = 0; kh < 7; kh++)
        #pragma unroll
        for (int kw = 0; kw < 7; kw++)
          acc += wsh[kh*7 + kw] * sin_[(li + kh)*134 + ww + kw];
      st[li*134 + 1 + ww] = gelu_exact(acc);
    }
  }
  __syncthreads();
  float* op = bodyY + (size_t)(bs*32 + r)*16640;
  for (int idx = t; idx < 16*128; idx += 256){
    int li = idx >> 7, ww = idx & 127;
    int ho = h0 + li;
    float acc = 0.f;
    #pragma unroll
    for (int kh = 0; kh < 3; kh++)
      #pragma unroll
      for (int kw = 0; kw < 3; kw++)
        acc += st[(li + kh)*134 + ww + kw];
    op[ho*128 + ww] = acc * (1.0f/9.0f);
  }
}

// Final: out[b,c] = (g0+g1)*x[b,c] + sum_s g_s * P2[e_s][c,:] (body_s * silu(P1[e_s] x))
__global__ __launch_bounds__(256) void k_combine(const float* __restrict__ x, const float* __restrict__ bodyY,
    const float* __restrict__ proj1, const float* __restrict__ proj2,
    const int* __restrict__ slot_e, const float* __restrict__ slot_g,
    float* __restrict__ out){
  int b = blockIdx.y;
  int hw = blockIdx.x * 256 + threadIdx.x;
  int ea = __builtin_amdgcn_readfirstlane(slot_e[b*2 + 0]);
  int eb = __builtin_amdgcn_readfirstlane(slot_e[b*2 + 1]);
  float ga = slot_g[b*2 + 0], gb = slot_g[b*2 + 1];
  float gs = ga + gb;
  const float* P1a = proj1 + ea*2048;
  const float* P1b = proj1 + eb*2048;
  const float* xb = x + (size_t)b*64*16384 + hw;

  float Ga[32], Gb[32];
  #pragma unroll
  for (int r = 0; r < 32; r++){ Ga[r] = 0.f; Gb[r] = 0.f; }
  for (int c = 0; c < 64; c++){
    float xc = xb[(size_t)c*16384];
    #pragma unroll
    for (int r = 0; r < 32; r++){
      Ga[r] += P1a[r*64 + c] * xc;
      Gb[r] += P1b[r*64 + c] * xc;
    }
  }
  const float* Ba = bodyY + (size_t)(b*2 + 0)*32*16640 + hw;
  const float* Bb = bodyY + (size_t)(b*2 + 1)*32*16640 + hw;
  float sa[32], sb[32];
  #pragma unroll
  for (int r = 0; r < 32; r++){
    sa[r] = Ba[(size_t)r*16640] * silu(Ga[r]);
    sb[r] = Bb[(size_t)r*16640] * silu(Gb[r]);
  }
  const float* P2a = proj2 + ea*2048;
  const float* P2b = proj2 + eb*2048;
  float* ob = out + (size_t)b*64*16384 + hw;
  for (int c = 0; c < 64; c++){
    float xc = xb[(size_t)c*16384];
    float acc0 = 0.f, acc1 = 0.f;
    #pragma unroll
    for (int r = 0; r < 32; r++){
      acc0 += P2a[c*32 + r] * sa[r];
      acc1 += P2b[c*32 + r] * sb[r];
    }
    ob[(size_t)c*16384] = gs*xc + ga*acc0 + gb*acc1;
  }
}

} // namespace

extern "C" void kernel_launch(void* const* d_in, const int* in_sizes, int n_in,
                              void* d_out, int out_size, void* d_ws, size_t ws_size,
                              hipStream_t stream) {
  (void)in_sizes; (void)n_in; (void)out_size; (void)ws_size;
  const float* x        = (const float*)d_in[0];
  const float* noise    = (const float*)d_in[1];
  const float* gate_w   = (const float*)d_in[2];
  const float* fg_w1    = (const float*)d_in[3];
  const float* fg_b1    = (const float*)d_in[4];
  const float* fg_w2    = (const float*)d_in[5];
  const float* proj0    = (const float*)d_in[6];
  const float* proj1    = (const float*)d_in[7];
  const float* proj2    = (const float*)d_in[8];
  const float* hg_gain  = (const float*)d_in[9];
  const float* hg_decay = (const float*)d_in[10];
  const float* hf_w1    = (const float*)d_in[11];
  const float* hf_b1    = (const float*)d_in[12];
  const float* hf_w2    = (const float*)d_in[13];
  const float* hf_b2    = (const float*)d_in[14];
  const float* lg_gain  = (const float*)d_in[15];
  const float* lg_decay = (const float*)d_in[16];
  const float* lf_w     = (const float*)d_in[17];
  const float* lf_b     = (const float*)d_in[18];
  float* out = (float*)d_out;

  // ws (floats):
  //  [0, 17039360)            X spectra [1024][65][128] f2 ; later overlaid by A [32 bs][32 r][16384]
  //  [17039360, 34078720)     Yspec/body [32 bs][32 r][65*128 f2]
  //  tail: xmean 1024 | part_w 65536 | slot_g 32 | slot_e 32 (int) | slot_of 64 (int)
  float* ws = (float*)d_ws;
  float2* X  = (float2*)ws;
  float*  A  = ws;
  float*  Yf = ws + 17039360;
  float2* Y2 = (float2*)Yf;
  float*  tail   = ws + 34078720;
  float*  xmean  = tail;
  float*  part_w = xmean + 1024;
  float*  slot_g = part_w + 65536;
  int*    slot_e = (int*)(slot_g + 32);
  int*    slot_of = slot_e + 32;

  // routing inputs (xmean from spectrum DC)
  k_fft2fwd<<<1024, 512, 0, stream>>>(x, X, part_w, xmean);
  k_routing<<<1, 128, 0, stream>>>(xmean, part_w, noise, gate_w, fg_w1, fg_b1, fg_w2,
                                   slot_e, slot_of, slot_g);

  // frequency-domain projections (X alive)
  k_projfreq<<<dim3(2,65,16), 256, 0, stream>>>(X, proj0 + 0*2048, Y2, slot_of, 0, hg_gain, hg_decay, 3.0f);
  k_projfreq<<<dim3(2,65,16), 256, 0, stream>>>(X, proj0 + 2*2048, Y2, slot_of, 2, lg_gain, lg_decay, 1.0f);

  // A for conv slots (overlays X; X dead after projfreq)
  k_projA<<<dim3(64,16), 256, 0, stream>>>(x, proj0, slot_e, A);

  // inverse FFTs for freq slots (bodies in place in Yspec)
  k_ifft2<<<1024, 512, 0, stream>>>(Y2, slot_e);

  // conv experts (bodies into Yspec slots)
  k_conv3<<<dim3(8,512), 256, 0, stream>>>(A, Yf, hf_w1, hf_b1, hf_w2, hf_b2, slot_of);
  k_conv7<<<dim3(8,512), 256, 0, stream>>>(A, Yf, lf_w, lf_b, slot_of);

  // final combine (includes shortcut and gating; writes out exactly once)
  k_combine<<<dim3(64,16), 256, 0, stream>>>(x, Yf, proj1, proj2, slot_e, slot_g, out);
}

// Round 5
// 465.405 us; speedup vs baseline: 2.0468x; 1.0088x over previous
//
#include <hip/hip_runtime.h>
#include <math.h>

// B=16, DIM=64, RANK=32, H=W=128, E=4, K=2, BINS=8, FREQ_DIM=64, KS=7
// Round 5: k_combine spill fix (in-place G->s, 64 live floats max);
// merged freq-projection kernel (one X pass for both freq experts).

namespace {

struct cpx { float x, y; };
struct Tw7 { cpx t[7]; };

__device__ __forceinline__ cpx cmul(cpx a, cpx b){ return {a.x*b.x - a.y*b.y, a.x*b.y + a.y*b.x}; }

__device__ __forceinline__ cpx tw(int k, float invN){
  float s, c;
  sincosf(-6.283185307179586f * (float)k * invN, &s, &c);
  return {c, s};
}

__device__ __forceinline__ void init_tw(Tw7 &T, int lane){
  T.t[0] = tw(lane,      1.0f/128.0f);
  T.t[1] = tw(lane & 31, 1.0f/64.0f);
  T.t[2] = tw(lane & 15, 1.0f/32.0f);
  T.t[3] = tw(lane & 7,  1.0f/16.0f);
  T.t[4] = tw(lane & 3,  1.0f/8.0f);
  T.t[5] = tw(lane & 1,  1.0f/4.0f);
  T.t[6] = {1.0f, 0.0f};
}

__device__ __forceinline__ int br6(int l){ return (int)(__brev((unsigned)l) >> 26); }

// 128-pt DIF FFT across one wave: lane holds a=in[l], b=in[l+64].
// Output: a = F[2*br6(l)], b = F[2*br6(l)+1].
__device__ __forceinline__ void fft128(cpx &a, cpx &b, int lane, const Tw7 &T){
  cpx u{a.x + b.x, a.y + b.y};
  cpx v{a.x - b.x, a.y - b.y};
  v = cmul(v, T.t[0]);
  a = u; b = v;
  int s = 1;
  #pragma unroll
  for (int m = 32; m >= 1; m >>= 1, s++){
    float pax = __shfl_xor(a.x, m);
    float pay = __shfl_xor(a.y, m);
    float pbx = __shfl_xor(b.x, m);
    float pby = __shfl_xor(b.y, m);
    cpx w = T.t[s];
    if (lane & m){
      cpx ta{pax - a.x, pay - a.y};
      cpx tb{pbx - b.x, pby - b.y};
      a = cmul(ta, w);
      b = cmul(tb, w);
    } else {
      a.x += pax; a.y += pay;
      b.x += pbx; b.y += pby;
    }
  }
}

// spectrum layout: row j (0..63, col0 packs Nyquist), col i. float2 elements.
#define LIDX(j,i) ((((j) << 7)) | (((i) ^ ((j) & 31)) & 127))
// packed row-FFT storage: pair p (0..63), freq j (0..127)
#define ZIDX(p,j) ((((p) << 7)) | (((j) ^ (p)) & 127))

__device__ __forceinline__ float gelu_exact(float v){
  return 0.5f * v * (1.0f + erff(v * 0.70710678118654752f));
}

__device__ __forceinline__ float silu(float v){
  return v / (1.0f + expf(-v));
}

// ---------------- kernels ----------------

// Fused 2-D rFFT per (b,c) + radial energy partials + xmean. 512 threads.
__global__ __launch_bounds__(512) void k_fft2fwd(const float* __restrict__ x, float2* __restrict__ X,
                                                 float* __restrict__ part_w, float* __restrict__ xmean){
  __shared__ float2 z[8192];
  int bc = blockIdx.x; int t = threadIdx.x;
  int lane = t & 63, wv = t >> 6;
  Tw7 T; init_tw(T, lane);
  const float* img = x + (size_t)bc * 16384;

  // row FFTs, two real rows packed per complex FFT: pair p -> rows 2p, 2p+1
  #pragma unroll 4
  for (int k = 0; k < 8; k++){
    int p = wv*8 + k;
    int h0 = 2*p, h1 = 2*p + 1;
    cpx a{img[h0*128 + lane],      img[h1*128 + lane]};
    cpx b{img[h0*128 + lane + 64], img[h1*128 + lane + 64]};
    fft128(a, b, lane, T);
    int j0 = 2*br6(lane), j1 = j0 + 1;
    z[ZIDX(p,j0)] = make_float2(a.x, a.y);
    z[ZIDX(p,j1)] = make_float2(b.x, b.y);
  }
  __syncthreads();

  // column FFTs: unpack two-rows trick on read; results staged in registers.
  float rax[8], ray[8], rbx[8], rby[8];
  #pragma unroll
  for (int k = 0; k < 8; k++){
    int jj = wv*8 + k;
    int p  = lane >> 1, s = lane & 1;
    int p2 = 32 + p;
    cpx a, b;
    if (jj == 0){
      float2 z0 = z[ZIDX(p,0)],  z64 = z[ZIDX(p,64)];
      float2 w0 = z[ZIDX(p2,0)], w64 = z[ZIDX(p2,64)];
      a = { s ? z0.y : z0.x, s ? z64.y : z64.x };
      b = { s ? w0.y : w0.x, s ? w64.y : w64.x };
    } else {
      int jm = 128 - jj;
      float2 z1 = z[ZIDX(p,jj)],  z2 = z[ZIDX(p,jm)];
      if (s == 0) a = { 0.5f*(z1.x + z2.x), 0.5f*(z1.y - z2.y) };
      else        a = { 0.5f*(z1.y + z2.y), 0.5f*(z2.x - z1.x) };
      float2 w1 = z[ZIDX(p2,jj)], w2 = z[ZIDX(p2,jm)];
      if (s == 0) b = { 0.5f*(w1.x + w2.x), 0.5f*(w1.y - w2.y) };
      else        b = { 0.5f*(w1.y + w2.y), 0.5f*(w2.x - w1.x) };
    }
    fft128(a, b, lane, T);
    rax[k] = a.x; ray[k] = a.y; rbx[k] = b.x; rby[k] = b.y;
  }
  __syncthreads();
  #pragma unroll
  for (int k = 0; k < 8; k++){
    int jj = wv*8 + k;
    int i0 = 2*br6(lane);
    z[LIDX(jj,i0)]   = make_float2(rax[k], ray[k]);
    z[LIDX(jj,i0+1)] = make_float2(rbx[k], rby[k]);
  }
  __syncthreads();

  if (t == 0) xmean[bc] = z[LIDX(0,0)].x * (1.0f/16384.0f);

  // radial energy
  float edges[9];
  float step = sqrtf(8192.0f) * 0.125f;
  #pragma unroll
  for (int k = 0; k <= 8; k++) edges[k] = step * (float)k;
  float acc[8] = {0,0,0,0,0,0,0,0};
  for (int idx = t; idx < 64*128; idx += 512){
    int j = idx >> 7, i = idx & 127;
    if (j == 0){
      float2 c0 = z[LIDX(0,i)];
      int in_ = (128 - i) & 127;
      float2 d0v = z[LIDX(0,in_)];
      float x0r = 0.5f*(c0.x + d0v.x), x0i = 0.5f*(c0.y - d0v.y);
      float x6r = 0.5f*(c0.y + d0v.y), x6i = 0.5f*(d0v.x - c0.x);
      float m0 = sqrtf(x0r*x0r + x0i*x0i) * (1.0f/16384.0f);
      float m6 = sqrtf(x6r*x6r + x6i*x6i) * (1.0f/16384.0f);
      float dyv = (float)(i - 64);
      float d0 = sqrtf(dyv*dyv + 4096.0f);
      float d6 = fabsf(dyv);
      #pragma unroll
      for (int k = 0; k < 8; k++){
        if (d0 >= edges[k] && d0 < edges[k+1]) acc[k] += m0;
        if (d6 >= edges[k] && d6 < edges[k+1]) acc[k] += m6;
      }
    } else {
      float2 zv = z[LIDX(j,i)];
      float mag = sqrtf(zv.x*zv.x + zv.y*zv.y) * (2.0f/16384.0f);
      float dy = (float)(i - 64), dx = (float)(j - 64);
      float d = sqrtf(dy*dy + dx*dx);
      #pragma unroll
      for (int k = 0; k < 8; k++)
        if (d >= edges[k] && d < edges[k+1]) acc[k] += mag;
    }
  }
  #pragma unroll
  for (int k = 0; k < 8; k++){
    float v = acc[k];
    for (int off = 32; off > 0; off >>= 1) v += __shfl_xor(v, off);
    if (lane == 0) part_w[(bc*8 + wv)*8 + k] = v;
  }

  // coalesced X write-out
  float2* Xo = X + (size_t)bc * (65*128);
  for (int idx = t; idx < 65*128; idx += 512){
    int j = idx >> 7, i = idx & 127;
    float2 v;
    if (j == 0){
      float2 c0 = z[LIDX(0,i)];
      int in_ = (128 - i) & 127;
      float2 d0v = z[LIDX(0,in_)];
      v = make_float2(0.5f*(c0.x + d0v.x), 0.5f*(c0.y - d0v.y));
    } else if (j == 64){
      float2 c0 = z[LIDX(0,i)];
      int in_ = (128 - i) & 127;
      float2 d0v = z[LIDX(0,in_)];
      v = make_float2(0.5f*(c0.y + d0v.y), 0.5f*(d0v.x - c0.x));
    } else {
      v = z[LIDX(j,i)];
    }
    Xo[idx] = v;
  }
}

__global__ __launch_bounds__(128) void k_routing(const float* __restrict__ xmean, const float* __restrict__ part_w,
    const float* __restrict__ noise, const float* __restrict__ gate_w,
    const float* __restrict__ fg_w1, const float* __restrict__ fg_b1, const float* __restrict__ fg_w2,
    int* __restrict__ slot_e, int* __restrict__ slot_of, float* __restrict__ slot_g){
  __shared__ float femb[16][8];
  __shared__ float hid[16][64];
  __shared__ float lgt[16][4];
  int t = threadIdx.x;
  {
    int b = t >> 3, k = t & 7;
    float s = 0.f;
    for (int c = 0; c < 64; c++)
      for (int w = 0; w < 8; w++)
        s += part_w[((b*64 + c)*8 + w)*8 + k];
    femb[b][k] = s * (1.0f/64.0f);
  }
  __syncthreads();
  for (int idx = t; idx < 16*64; idx += 128){
    int b = idx >> 6, f = idx & 63;
    float s = fg_b1[f];
    for (int k = 0; k < 8; k++) s += femb[b][k] * fg_w1[f*8 + k];
    hid[b][f] = fmaxf(s, 0.f);
  }
  __syncthreads();
  if (t < 64){
    int b = t >> 2, e = t & 3;
    float s = 0.f;
    for (int c = 0; c < 64; c++) s += xmean[b*64 + c] * gate_w[e*64 + c];
    for (int f = 0; f < 64; f++) s += hid[b][f] * fg_w2[e*64 + f];
    lgt[b][e] = s + noise[b*4 + e] * 0.25f;   // NOISE_STD = 1/E
  }
  __syncthreads();
  if (t < 16){
    int b = t;
    float m = fmaxf(fmaxf(lgt[b][0], lgt[b][1]), fmaxf(lgt[b][2], lgt[b][3]));
    float p[4]; float sum = 0.f;
    for (int e = 0; e < 4; e++){ p[e] = expf(lgt[b][e] - m); sum += p[e]; }
    for (int e = 0; e < 4; e++) p[e] /= sum;
    int i1 = 0;
    for (int e = 1; e < 4; e++) if (p[e] > p[i1]) i1 = e;   // ties -> lowest idx (lax.top_k)
    int i2 = -1;
    for (int e = 0; e < 4; e++){ if (e == i1) continue; if (i2 < 0 || p[e] > p[i2]) i2 = e; }
    slot_e[b*2 + 0] = i1;
    slot_e[b*2 + 1] = i2;
    slot_g[b*2 + 0] = p[i1];
    slot_g[b*2 + 1] = p[i2];
    for (int e = 0; e < 4; e++) slot_of[b*4 + e] = (e == i1) ? 0 : ((e == i2) ? 1 : -1);
  }
}

// Both freq experts in one pass over X. Yspec[bs][r][j][i]; bs = b*2+slot.
__global__ __launch_bounds__(256) void k_projfreq(const float2* __restrict__ X, const float* __restrict__ proj0,
    float2* __restrict__ Y, const int* __restrict__ slot_e,
    const float* __restrict__ hg_gain, const float* __restrict__ hg_decay,
    const float* __restrict__ lg_gain, const float* __restrict__ lg_decay){
  int b = blockIdx.z;
  int e0 = slot_e[b*2 + 0], e1 = slot_e[b*2 + 1];
  bool f0 = (e0 == 0) || (e0 == 2);
  bool f1 = (e1 == 0) || (e1 == 2);
  if (!f0 && !f1) return;
  int j = blockIdx.y;
  int i0 = blockIdx.x * 64;
  int t = threadIdx.x;
  __shared__ float2 sx[64][64];
  for (int idx = t; idx < 4096; idx += 256){
    int c = idx >> 6, ii = idx & 63;
    sx[c][ii] = X[(((size_t)(b*64 + c))*65 + j)*128 + i0 + ii];
  }
  __syncthreads();
  int ii = t & 63;
  int rg = __builtin_amdgcn_readfirstlane(t >> 6);
  int i = i0 + ii;
  float fy = (float)(i < 64 ? i : i - 128) * (1.0f/128.0f);
  float fx = (float)j * (1.0f/128.0f);
  float fg = sqrtf(fy*fy + fx*fx);

  #pragma unroll
  for (int s = 0; s < 2; s++){
    int e = (s == 0) ? e0 : e1;
    if (e != 0 && e != 2) continue;
    float gain, decay, cmax;
    if (e == 0){ gain = *hg_gain; decay = *hg_decay; cmax = 3.0f; }
    else       { gain = *lg_gain; decay = *lg_decay; cmax = 1.0f; }
    float filt = (1.0f - expf(-gain*fg)) * expf(-decay*fg);
    filt = fminf(fmaxf(filt, 0.0f), cmax) * (1.0f/16384.0f);
    int bs = b*2 + s;
    const float* W = proj0 + e*2048 + rg*8*64;
    float ax[8] = {0,0,0,0,0,0,0,0};
    float ay[8] = {0,0,0,0,0,0,0,0};
    for (int c = 0; c < 64; c++){
      float2 xv = sx[c][ii];
      #pragma unroll
      for (int r8 = 0; r8 < 8; r8++){
        float wv = W[r8*64 + c];          // wave-uniform -> s_load
        ax[r8] += wv * xv.x;
        ay[r8] += wv * xv.y;
      }
    }
    #pragma unroll
    for (int r8 = 0; r8 < 8; r8++){
      int r = rg*8 + r8;
      Y[((size_t)(bs*32 + r))*8320 + j*128 + i] = make_float2(ax[r8]*filt, ay[r8]*filt);
    }
  }
}

// Fused inverse 2-D FFT per (bs,r) for freq slots; body written IN PLACE. 512 threads.
__global__ __launch_bounds__(512) void k_ifft2(float2* __restrict__ Y, const int* __restrict__ slot_e){
  int blk = blockIdx.x;
  int bs = blk >> 5, r = blk & 31;
  int es = slot_e[bs];
  if (es == 1 || es == 3) return;     // conv slots skip
  __shared__ float2 z[8192];
  int t = threadIdx.x; int lane = t & 63, wv = t >> 6;
  Tw7 T; init_tw(T, lane);
  float2* Yb = Y + (size_t)(bs*32 + r) * 8320;

  // load; row 0 packed: P[i] = Y[0][i] + i*Y[64][i]
  for (int idx = t; idx < 8192; idx += 512){
    int j = idx >> 7, i = idx & 127;
    if (j == 0){
      float2 y0 = Yb[i];
      float2 y6 = Yb[8192 + i];
      z[LIDX(0,i)] = make_float2(y0.x - y6.y, y0.y + y6.x);
    } else {
      z[LIDX(j,i)] = Yb[idx];
    }
  }
  __syncthreads();

  // inverse column FFTs (unnormalized), in place per column
  #pragma unroll
  for (int k = 0; k < 8; k++){
    int jj = wv*8 + k;
    float2 z0 = z[LIDX(jj,lane)], z1 = z[LIDX(jj,lane+64)];
    cpx a{z0.x, -z0.y}, b{z1.x, -z1.y};
    fft128(a, b, lane, T);
    int i0 = 2*br6(lane);
    z[LIDX(jj,i0)]   = make_float2(a.x, -a.y);
    z[LIDX(jj,i0+1)] = make_float2(b.x, -b.y);
  }
  __syncthreads();

  // inverse row transform: two real output rows per complex inverse FFT
  float* body = (float*)Yb;
  #pragma unroll 2
  for (int k = 0; k < 8; k++){
    int p = wv*8 + k;
    int h = 2*p, h1 = 2*p + 1;
    cpx a, b;
    if (lane == 0){
      float2 c0 = z[LIDX(0,h)], c1 = z[LIDX(0,h1)];
      a = { c0.x, c1.x };
      b = { c0.y, c1.y };
    } else {
      float2 yh = z[LIDX(lane,h)], y1 = z[LIDX(lane,h1)];
      a = { yh.x - y1.y, yh.y + y1.x };
      int lm = 64 - lane;
      float2 zh = z[LIDX(lm,h)], z1_ = z[LIDX(lm,h1)];
      b = { zh.x + z1_.y, z1_.x - zh.y };
    }
    a.y = -a.y; b.y = -b.y;        // conj
    fft128(a, b, lane, T);
    int n0 = 2*br6(lane);
    body[h*128 + n0]      = a.x;   // conj on output: real part
    body[h1*128 + n0]     = -a.y;
    body[h*128 + n0 + 1]  = b.x;
    body[h1*128 + n0 + 1] = -b.y;
  }
}

// A[bs][r] = P0[e_s] x[b]  for conv slots only.
__global__ __launch_bounds__(256) void k_projA(const float* __restrict__ x, const float* __restrict__ proj0,
    const int* __restrict__ slot_e, float* __restrict__ A){
  int b = blockIdx.y;
  int e0 = slot_e[b*2 + 0], e1 = slot_e[b*2 + 1];
  bool c0 = (e0 == 1) || (e0 == 3);
  bool c1 = (e1 == 1) || (e1 == 3);
  if (!c0 && !c1) return;
  int hw = blockIdx.x * 256 + threadIdx.x;
  const float* xb = x + (size_t)b*64*16384 + hw;
  float xv[64];
  #pragma unroll
  for (int c = 0; c < 64; c++) xv[c] = xb[(size_t)c*16384];
  if (c0){
    const float* W = proj0 + __builtin_amdgcn_readfirstlane(e0)*2048;
    float* Ab = A + (size_t)(b*2 + 0)*32*16384 + hw;
    for (int r = 0; r < 32; r++){
      float a = 0.f;
      #pragma unroll
      for (int c = 0; c < 64; c++) a += W[r*64 + c] * xv[c];
      Ab[(size_t)r*16384] = a;
    }
  }
  if (c1){
    const float* W = proj0 + __builtin_amdgcn_readfirstlane(e1)*2048;
    float* Ab = A + (size_t)(b*2 + 1)*32*16384 + hw;
    for (int r = 0; r < 32; r++){
      float a = 0.f;
      #pragma unroll
      for (int c = 0; c < 64; c++) a += W[r*64 + c] * xv[c];
      Ab[(size_t)r*16384] = a;
    }
  }
}

// Expert 1 fused: dw3 -> gelu -> dw3, LDS-tiled (16 out rows x 128)
__global__ __launch_bounds__(256) void k_conv3(const float* __restrict__ A, float* __restrict__ bodyY,
    const float* __restrict__ w1g, const float* __restrict__ b1g,
    const float* __restrict__ w2g, const float* __restrict__ b2g,
    const int* __restrict__ slot_of){
  int by = blockIdx.y; int b = by >> 5, r = by & 31;
  int slot = slot_of[b*4 + 1];
  if (slot < 0) return;
  int bs = b*2 + slot;
  int h0 = blockIdx.x * 16;
  int t = threadIdx.x;
  __shared__ float sin_[20*130];
  __shared__ float st[18*130];
  for (int i = t; i < 20*130; i += 256) sin_[i] = 0.f;
  for (int i = t; i < 18*130; i += 256) st[i] = 0.f;
  float w1[9], w2[9];
  #pragma unroll
  for (int k = 0; k < 9; k++){ w1[k] = w1g[r*9 + k]; w2[k] = w2g[r*9 + k]; }
  float b1 = b1g[r], b2 = b2g[r];
  __syncthreads();
  const float* ip = A + (size_t)(bs*32 + r)*16384;
  for (int idx = t; idx < 20*128; idx += 256){
    int li = idx >> 7, ww = idx & 127;
    int ih = h0 - 2 + li;
    if (ih >= 0 && ih < 128) sin_[li*130 + 1 + ww] = ip[ih*128 + ww];
  }
  __syncthreads();
  for (int idx = t; idx < 18*128; idx += 256){
    int li = idx >> 7, ww = idx & 127;
    int hs = h0 - 1 + li;
    if (hs >= 0 && hs < 128){
      float acc = b1;
      #pragma unroll
      for (int kh = 0; kh < 3; kh++)
        #pragma unroll
        for (int kw = 0; kw < 3; kw++)
          acc += w1[kh*3 + kw] * sin_[(li + kh)*130 + ww + kw];
      st[li*130 + 1 + ww] = gelu_exact(acc);
    }
  }
  __syncthreads();
  float* op = bodyY + (size_t)(bs*32 + r)*16640;
  for (int idx = t; idx < 16*128; idx += 256){
    int li = idx >> 7, ww = idx & 127;
    int ho = h0 + li;
    float acc = b2;
    #pragma unroll
    for (int kh = 0; kh < 3; kh++)
      #pragma unroll
      for (int kw = 0; kw < 3; kw++)
        acc += w2[kh*3 + kw] * st[(li + kh)*130 + ww + kw];
    op[ho*128 + ww] = acc;
  }
}

// Expert 3 fused: dw7 -> gelu -> avgpool3 (count_include_pad)
__global__ __launch_bounds__(256) void k_conv7(const float* __restrict__ A, float* __restrict__ bodyY,
    const float* __restrict__ wg, const float* __restrict__ bg,
    const int* __restrict__ slot_of){
  int by = blockIdx.y; int b = by >> 5, r = by & 31;
  int slot = slot_of[b*4 + 3];
  if (slot < 0) return;
  int bs = b*2 + slot;
  int h0 = blockIdx.x * 16;
  int t = threadIdx.x;
  __shared__ float sin_[24*134];
  __shared__ float st[18*134];
  __shared__ float wsh[49];
  for (int i = t; i < 24*134; i += 256) sin_[i] = 0.f;
  for (int i = t; i < 18*134; i += 256) st[i] = 0.f;
  if (t < 49) wsh[t] = wg[r*49 + t];
  float bias = bg[r];
  __syncthreads();
  const float* ip = A + (size_t)(bs*32 + r)*16384;
  for (int idx = t; idx < 24*128; idx += 256){
    int li = idx >> 7, ww = idx & 127;
    int ih = h0 - 4 + li;
    if (ih >= 0 && ih < 128) sin_[li*134 + 3 + ww] = ip[ih*128 + ww];
  }
  __syncthreads();
  for (int idx = t; idx < 18*128; idx += 256){
    int li = idx >> 7, ww = idx & 127;
    int hs = h0 - 1 + li;
    if (hs >= 0 && hs < 128){
      float acc = bias;
      #pragma unroll
      for (int kh = 0; kh < 7; kh++)
        #pragma unroll
        for (int kw = 0; kw < 7; kw++)
          acc += wsh[kh*7 + kw] * sin_[(li + kh)*134 + ww + kw];
      st[li*134 + 1 + ww] = gelu_exact(acc);
    }
  }
  __syncthreads();
  float* op = bodyY + (size_t)(bs*32 + r)*16640;
  for (int idx = t; idx < 16*128; idx += 256){
    int li = idx >> 7, ww = idx & 127;
    int ho = h0 + li;
    float acc = 0.f;
    #pragma unroll
    for (int kh = 0; kh < 3; kh++)
      #pragma unroll
      for (int kw = 0; kw < 3; kw++)
        acc += st[(li + kh)*134 + ww + kw];
    op[ho*128 + ww] = acc * (1.0f/9.0f);
  }
}

// Final: out[b,c] = (g0+g1)*x[b,c] + sum_s g_s * P2[e_s][c,:] (body_s * silu(P1[e_s] x))
// In-place G->s conversion keeps live state at 64 floats (no spill).
__global__ __launch_bounds__(256) void k_combine(const float* __restrict__ x, const float* __restrict__ bodyY,
    const float* __restrict__ proj1, const float* __restrict__ proj2,
    const int* __restrict__ slot_e, const float* __restrict__ slot_g,
    float* __restrict__ out){
  int b = blockIdx.y;
  int hw = blockIdx.x * 256 + threadIdx.x;
  int ea = __builtin_amdgcn_readfirstlane(slot_e[b*2 + 0]);
  int eb = __builtin_amdgcn_readfirstlane(slot_e[b*2 + 1]);
  float ga = slot_g[b*2 + 0], gb = slot_g[b*2 + 1];
  float gs = ga + gb;
  const float* P1a = proj1 + ea*2048;
  const float* P1b = proj1 + eb*2048;
  const float* xb = x + (size_t)b*64*16384 + hw;

  float Ga[32], Gb[32];
  #pragma unroll
  for (int r = 0; r < 32; r++){ Ga[r] = 0.f; Gb[r] = 0.f; }
  for (int c = 0; c < 64; c++){
    float xc = xb[(size_t)c*16384];
    #pragma unroll
    for (int r = 0; r < 32; r++){
      Ga[r] += P1a[r*64 + c] * xc;
      Gb[r] += P1b[r*64 + c] * xc;
    }
  }
  // in-place: G -> body * silu(G)
  const float* Ba = bodyY + (size_t)(b*2 + 0)*32*16640 + hw;
  const float* Bb = bodyY + (size_t)(b*2 + 1)*32*16640 + hw;
  #pragma unroll
  for (int r = 0; r < 32; r++){
    Ga[r] = Ba[(size_t)r*16640] * silu(Ga[r]);
    Gb[r] = Bb[(size_t)r*16640] * silu(Gb[r]);
  }
  const float* P2a = proj2 + ea*2048;
  const float* P2b = proj2 + eb*2048;
  float* ob = out + (size_t)b*64*16384 + hw;
  for (int c = 0; c < 64; c++){
    float xc = xb[(size_t)c*16384];
    float acc0 = 0.f, acc1 = 0.f;
    #pragma unroll
    for (int r = 0; r < 32; r++){
      acc0 += P2a[c*32 + r] * Ga[r];
      acc1 += P2b[c*32 + r] * Gb[r];
    }
    ob[(size_t)c*16384] = gs*xc + ga*acc0 + gb*acc1;
  }
}

} // namespace

extern "C" void kernel_launch(void* const* d_in, const int* in_sizes, int n_in,
                              void* d_out, int out_size, void* d_ws, size_t ws_size,
                              hipStream_t stream) {
  (void)in_sizes; (void)n_in; (void)out_size; (void)ws_size;
  const float* x        = (const float*)d_in[0];
  const float* noise    = (const float*)d_in[1];
  const float* gate_w   = (const float*)d_in[2];
  const float* fg_w1    = (const float*)d_in[3];
  const float* fg_b1    = (const float*)d_in[4];
  const float* fg_w2    = (const float*)d_in[5];
  const float* proj0    = (const float*)d_in[6];
  const float* proj1    = (const float*)d_in[7];
  const float* proj2    = (const float*)d_in[8];
  const float* hg_gain  = (const float*)d_in[9];
  const float* hg_decay = (const float*)d_in[10];
  const float* hf_w1    = (const float*)d_in[11];
  const float* hf_b1    = (const float*)d_in[12];
  const float* hf_w2    = (const float*)d_in[13];
  const float* hf_b2    = (const float*)d_in[14];
  const float* lg_gain  = (const float*)d_in[15];
  const float* lg_decay = (const float*)d_in[16];
  const float* lf_w     = (const float*)d_in[17];
  const float* lf_b     = (const float*)d_in[18];
  float* out = (float*)d_out;

  // ws (floats):
  //  [0, 17039360)            X spectra [1024][65][128] f2 ; later overlaid by A [32 bs][32 r][16384]
  //  [17039360, 34078720)     Yspec/body [32 bs][32 r][65*128 f2]
  //  tail: xmean 1024 | part_w 65536 | slot_g 32 | slot_e 32 (int) | slot_of 64 (int)
  float* ws = (float*)d_ws;
  float2* X  = (float2*)ws;
  float*  A  = ws;
  float*  Yf = ws + 17039360;
  float2* Y2 = (float2*)Yf;
  float*  tail   = ws + 34078720;
  float*  xmean  = tail;
  float*  part_w = xmean + 1024;
  float*  slot_g = part_w + 65536;
  int*    slot_e = (int*)(slot_g + 32);
  int*    slot_of = slot_e + 32;

  // routing inputs (xmean from spectrum DC)
  k_fft2fwd<<<1024, 512, 0, stream>>>(x, X, part_w, xmean);
  k_routing<<<1, 128, 0, stream>>>(xmean, part_w, noise, gate_w, fg_w1, fg_b1, fg_w2,
                                   slot_e, slot_of, slot_g);

  // frequency-domain projections, both freq experts in one X pass
  k_projfreq<<<dim3(2,65,16), 256, 0, stream>>>(X, proj0, Y2, slot_e,
                                                hg_gain, hg_decay, lg_gain, lg_decay);

  // A for conv slots (overlays X; X dead after projfreq)
  k_projA<<<dim3(64,16), 256, 0, stream>>>(x, proj0, slot_e, A);

  // inverse FFTs for freq slots (bodies in place in Yspec)
  k_ifft2<<<1024, 512, 0, stream>>>(Y2, slot_e);

  // conv experts (bodies into Yspec slots)
  k_conv3<<<dim3(8,512), 256, 0, stream>>>(A, Yf, hf_w1, hf_b1, hf_w2, hf_b2, slot_of);
  k_conv7<<<dim3(8,512), 256, 0, stream>>>(A, Yf, lf_w, lf_b, slot_of);

  // final combine (includes shortcut and gating; writes out exactly once)
  k_combine<<<dim3(64,16), 256, 0, stream>>>(x, Yf, proj1, proj2, slot_e, slot_g, out);
}

// Round 6
// 401.052 us; speedup vs baseline: 2.3753x; 1.1605x over previous
//
#include <hip/hip_runtime.h>
#include <math.h>

// B=16, DIM=64, RANK=32, H=W=128, E=4, K=2, BINS=8, FREQ_DIM=64, KS=7
// Round 6: weight delivery via LDS broadcast (ds_read_b128) in k_combine and
// k_projfreq -- kills the scattered s_load serialization (c-outer, stride-256B
// weight reads) that left k_combine at 20% VALUBusy.

namespace {

struct cpx { float x, y; };
struct Tw7 { cpx t[7]; };

__device__ __forceinline__ cpx cmul(cpx a, cpx b){ return {a.x*b.x - a.y*b.y, a.x*b.y + a.y*b.x}; }

__device__ __forceinline__ cpx tw(int k, float invN){
  float s, c;
  sincosf(-6.283185307179586f * (float)k * invN, &s, &c);
  return {c, s};
}

__device__ __forceinline__ void init_tw(Tw7 &T, int lane){
  T.t[0] = tw(lane,      1.0f/128.0f);
  T.t[1] = tw(lane & 31, 1.0f/64.0f);
  T.t[2] = tw(lane & 15, 1.0f/32.0f);
  T.t[3] = tw(lane & 7,  1.0f/16.0f);
  T.t[4] = tw(lane & 3,  1.0f/8.0f);
  T.t[5] = tw(lane & 1,  1.0f/4.0f);
  T.t[6] = {1.0f, 0.0f};
}

__device__ __forceinline__ int br6(int l){ return (int)(__brev((unsigned)l) >> 26); }

// 128-pt DIF FFT across one wave: lane holds a=in[l], b=in[l+64].
// Output: a = F[2*br6(l)], b = F[2*br6(l)+1].
__device__ __forceinline__ void fft128(cpx &a, cpx &b, int lane, const Tw7 &T){
  cpx u{a.x + b.x, a.y + b.y};
  cpx v{a.x - b.x, a.y - b.y};
  v = cmul(v, T.t[0]);
  a = u; b = v;
  int s = 1;
  #pragma unroll
  for (int m = 32; m >= 1; m >>= 1, s++){
    float pax = __shfl_xor(a.x, m);
    float pay = __shfl_xor(a.y, m);
    float pbx = __shfl_xor(b.x, m);
    float pby = __shfl_xor(b.y, m);
    cpx w = T.t[s];
    if (lane & m){
      cpx ta{pax - a.x, pay - a.y};
      cpx tb{pbx - b.x, pby - b.y};
      a = cmul(ta, w);
      b = cmul(tb, w);
    } else {
      a.x += pax; a.y += pay;
      b.x += pbx; b.y += pby;
    }
  }
}

// spectrum layout: row j (0..63, col0 packs Nyquist), col i. float2 elements.
#define LIDX(j,i) ((((j) << 7)) | (((i) ^ ((j) & 31)) & 127))
// packed row-FFT storage: pair p (0..63), freq j (0..127)
#define ZIDX(p,j) ((((p) << 7)) | (((j) ^ (p)) & 127))

__device__ __forceinline__ float gelu_exact(float v){
  return 0.5f * v * (1.0f + erff(v * 0.70710678118654752f));
}

__device__ __forceinline__ float silu(float v){
  return v / (1.0f + expf(-v));
}

// ---------------- kernels ----------------

// Fused 2-D rFFT per (b,c) + radial energy partials + xmean. 512 threads.
__global__ __launch_bounds__(512) void k_fft2fwd(const float* __restrict__ x, float2* __restrict__ X,
                                                 float* __restrict__ part_w, float* __restrict__ xmean){
  __shared__ float2 z[8192];
  int bc = blockIdx.x; int t = threadIdx.x;
  int lane = t & 63, wv = t >> 6;
  Tw7 T; init_tw(T, lane);
  const float* img = x + (size_t)bc * 16384;

  // row FFTs, two real rows packed per complex FFT: pair p -> rows 2p, 2p+1
  #pragma unroll 4
  for (int k = 0; k < 8; k++){
    int p = wv*8 + k;
    int h0 = 2*p, h1 = 2*p + 1;
    cpx a{img[h0*128 + lane],      img[h1*128 + lane]};
    cpx b{img[h0*128 + lane + 64], img[h1*128 + lane + 64]};
    fft128(a, b, lane, T);
    int j0 = 2*br6(lane), j1 = j0 + 1;
    z[ZIDX(p,j0)] = make_float2(a.x, a.y);
    z[ZIDX(p,j1)] = make_float2(b.x, b.y);
  }
  __syncthreads();

  // column FFTs: unpack two-rows trick on read; results staged in registers.
  float rax[8], ray[8], rbx[8], rby[8];
  #pragma unroll
  for (int k = 0; k < 8; k++){
    int jj = wv*8 + k;
    int p  = lane >> 1, s = lane & 1;
    int p2 = 32 + p;
    cpx a, b;
    if (jj == 0){
      float2 z0 = z[ZIDX(p,0)],  z64 = z[ZIDX(p,64)];
      float2 w0 = z[ZIDX(p2,0)], w64 = z[ZIDX(p2,64)];
      a = { s ? z0.y : z0.x, s ? z64.y : z64.x };
      b = { s ? w0.y : w0.x, s ? w64.y : w64.x };
    } else {
      int jm = 128 - jj;
      float2 z1 = z[ZIDX(p,jj)],  z2 = z[ZIDX(p,jm)];
      if (s == 0) a = { 0.5f*(z1.x + z2.x), 0.5f*(z1.y - z2.y) };
      else        a = { 0.5f*(z1.y + z2.y), 0.5f*(z2.x - z1.x) };
      float2 w1 = z[ZIDX(p2,jj)], w2 = z[ZIDX(p2,jm)];
      if (s == 0) b = { 0.5f*(w1.x + w2.x), 0.5f*(w1.y - w2.y) };
      else        b = { 0.5f*(w1.y + w2.y), 0.5f*(w2.x - w1.x) };
    }
    fft128(a, b, lane, T);
    rax[k] = a.x; ray[k] = a.y; rbx[k] = b.x; rby[k] = b.y;
  }
  __syncthreads();
  #pragma unroll
  for (int k = 0; k < 8; k++){
    int jj = wv*8 + k;
    int i0 = 2*br6(lane);
    z[LIDX(jj,i0)]   = make_float2(rax[k], ray[k]);
    z[LIDX(jj,i0+1)] = make_float2(rbx[k], rby[k]);
  }
  __syncthreads();

  if (t == 0) xmean[bc] = z[LIDX(0,0)].x * (1.0f/16384.0f);

  // radial energy
  float edges[9];
  float step = sqrtf(8192.0f) * 0.125f;
  #pragma unroll
  for (int k = 0; k <= 8; k++) edges[k] = step * (float)k;
  float acc[8] = {0,0,0,0,0,0,0,0};
  for (int idx = t; idx < 64*128; idx += 512){
    int j = idx >> 7, i = idx & 127;
    if (j == 0){
      float2 c0 = z[LIDX(0,i)];
      int in_ = (128 - i) & 127;
      float2 d0v = z[LIDX(0,in_)];
      float x0r = 0.5f*(c0.x + d0v.x), x0i = 0.5f*(c0.y - d0v.y);
      float x6r = 0.5f*(c0.y + d0v.y), x6i = 0.5f*(d0v.x - c0.x);
      float m0 = sqrtf(x0r*x0r + x0i*x0i) * (1.0f/16384.0f);
      float m6 = sqrtf(x6r*x6r + x6i*x6i) * (1.0f/16384.0f);
      float dyv = (float)(i - 64);
      float d0 = sqrtf(dyv*dyv + 4096.0f);
      float d6 = fabsf(dyv);
      #pragma unroll
      for (int k = 0; k < 8; k++){
        if (d0 >= edges[k] && d0 < edges[k+1]) acc[k] += m0;
        if (d6 >= edges[k] && d6 < edges[k+1]) acc[k] += m6;
      }
    } else {
      float2 zv = z[LIDX(j,i)];
      float mag = sqrtf(zv.x*zv.x + zv.y*zv.y) * (2.0f/16384.0f);
      float dy = (float)(i - 64), dx = (float)(j - 64);
      float d = sqrtf(dy*dy + dx*dx);
      #pragma unroll
      for (int k = 0; k < 8; k++)
        if (d >= edges[k] && d < edges[k+1]) acc[k] += mag;
    }
  }
  #pragma unroll
  for (int k = 0; k < 8; k++){
    float v = acc[k];
    for (int off = 32; off > 0; off >>= 1) v += __shfl_xor(v, off);
    if (lane == 0) part_w[(bc*8 + wv)*8 + k] = v;
  }

  // coalesced X write-out
  float2* Xo = X + (size_t)bc * (65*128);
  for (int idx = t; idx < 65*128; idx += 512){
    int j = idx >> 7, i = idx & 127;
    float2 v;
    if (j == 0){
      float2 c0 = z[LIDX(0,i)];
      int in_ = (128 - i) & 127;
      float2 d0v = z[LIDX(0,in_)];
      v = make_float2(0.5f*(c0.x + d0v.x), 0.5f*(c0.y - d0v.y));
    } else if (j == 64){
      float2 c0 = z[LIDX(0,i)];
      int in_ = (128 - i) & 127;
      float2 d0v = z[LIDX(0,in_)];
      v = make_float2(0.5f*(c0.y + d0v.y), 0.5f*(d0v.x - c0.x));
    } else {
      v = z[LIDX(j,i)];
    }
    Xo[idx] = v;
  }
}

__global__ __launch_bounds__(128) void k_routing(const float* __restrict__ xmean, const float* __restrict__ part_w,
    const float* __restrict__ noise, const float* __restrict__ gate_w,
    const float* __restrict__ fg_w1, const float* __restrict__ fg_b1, const float* __restrict__ fg_w2,
    int* __restrict__ slot_e, int* __restrict__ slot_of, float* __restrict__ slot_g){
  __shared__ float femb[16][8];
  __shared__ float hid[16][64];
  __shared__ float lgt[16][4];
  int t = threadIdx.x;
  {
    int b = t >> 3, k = t & 7;
    float s = 0.f;
    for (int c = 0; c < 64; c++)
      for (int w = 0; w < 8; w++)
        s += part_w[((b*64 + c)*8 + w)*8 + k];
    femb[b][k] = s * (1.0f/64.0f);
  }
  __syncthreads();
  for (int idx = t; idx < 16*64; idx += 128){
    int b = idx >> 6, f = idx & 63;
    float s = fg_b1[f];
    for (int k = 0; k < 8; k++) s += femb[b][k] * fg_w1[f*8 + k];
    hid[b][f] = fmaxf(s, 0.f);
  }
  __syncthreads();
  if (t < 64){
    int b = t >> 2, e = t & 3;
    float s = 0.f;
    for (int c = 0; c < 64; c++) s += xmean[b*64 + c] * gate_w[e*64 + c];
    for (int f = 0; f < 64; f++) s += hid[b][f] * fg_w2[e*64 + f];
    lgt[b][e] = s + noise[b*4 + e] * 0.25f;   // NOISE_STD = 1/E
  }
  __syncthreads();
  if (t < 16){
    int b = t;
    float m = fmaxf(fmaxf(lgt[b][0], lgt[b][1]), fmaxf(lgt[b][2], lgt[b][3]));
    float p[4]; float sum = 0.f;
    for (int e = 0; e < 4; e++){ p[e] = expf(lgt[b][e] - m); sum += p[e]; }
    for (int e = 0; e < 4; e++) p[e] /= sum;
    int i1 = 0;
    for (int e = 1; e < 4; e++) if (p[e] > p[i1]) i1 = e;   // ties -> lowest idx (lax.top_k)
    int i2 = -1;
    for (int e = 0; e < 4; e++){ if (e == i1) continue; if (i2 < 0 || p[e] > p[i2]) i2 = e; }
    slot_e[b*2 + 0] = i1;
    slot_e[b*2 + 1] = i2;
    slot_g[b*2 + 0] = p[i1];
    slot_g[b*2 + 1] = p[i2];
    for (int e = 0; e < 4; e++) slot_of[b*4 + e] = (e == i1) ? 0 : ((e == i2) ? 1 : -1);
  }
}

// Both freq experts in one pass over X, weights transposed in LDS.
// Yspec[bs][r][j][i]; bs = b*2+slot. 256 thr: group g=t>>5 handles rows g*4..g*4+3; ii=t&31.
__global__ __launch_bounds__(256) void k_projfreq(const float2* __restrict__ X, const float* __restrict__ proj0,
    float2* __restrict__ Y, const int* __restrict__ slot_e,
    const float* __restrict__ hg_gain, const float* __restrict__ hg_decay,
    const float* __restrict__ lg_gain, const float* __restrict__ lg_decay){
  int b = blockIdx.z;
  int e0 = slot_e[b*2 + 0], e1 = slot_e[b*2 + 1];
  bool f0 = (e0 == 0) || (e0 == 2);
  bool f1 = (e1 == 0) || (e1 == 2);
  if (!f0 && !f1) return;
  int j = blockIdx.y;
  int i0 = blockIdx.x * 32;
  int t = threadIdx.x;
  __shared__ __align__(16) float2 sx[64][32];
  __shared__ __align__(16) float wt[2][64*36];    // transposed P0: [c][r], pad 36
  {
    const float* W0 = proj0 + (f0 ? e0 : e1)*2048;
    const float* W1 = proj0 + (f1 ? e1 : e0)*2048;
    for (int idx = t; idx < 2048; idx += 256){
      int r = idx >> 6, c = idx & 63;
      wt[0][c*36 + r] = W0[idx];
      wt[1][c*36 + r] = W1[idx];
    }
  }
  for (int idx = t; idx < 2048; idx += 256){
    int c = idx >> 5, ii = idx & 31;
    sx[c][ii] = X[(((size_t)(b*64 + c))*65 + j)*128 + i0 + ii];
  }
  __syncthreads();
  int ii = t & 31;
  int g = t >> 5;                      // 8 groups x 4 rows
  int i = i0 + ii;
  float fy = (float)(i < 64 ? i : i - 128) * (1.0f/128.0f);
  float fx = (float)j * (1.0f/128.0f);
  float fg = sqrtf(fy*fy + fx*fx);

  float a0x[4] = {0,0,0,0}, a0y[4] = {0,0,0,0};
  float a1x[4] = {0,0,0,0}, a1y[4] = {0,0,0,0};
  for (int c = 0; c < 64; c++){
    float2 xv = sx[c][ii];
    float4 w0 = *(const float4*)&wt[0][c*36 + g*4];
    float4 w1 = *(const float4*)&wt[1][c*36 + g*4];
    a0x[0] += w0.x*xv.x; a0y[0] += w0.x*xv.y;
    a0x[1] += w0.y*xv.x; a0y[1] += w0.y*xv.y;
    a0x[2] += w0.z*xv.x; a0y[2] += w0.z*xv.y;
    a0x[3] += w0.w*xv.x; a0y[3] += w0.w*xv.y;
    a1x[0] += w1.x*xv.x; a1y[0] += w1.x*xv.y;
    a1x[1] += w1.y*xv.x; a1y[1] += w1.y*xv.y;
    a1x[2] += w1.z*xv.x; a1y[2] += w1.z*xv.y;
    a1x[3] += w1.w*xv.x; a1y[3] += w1.w*xv.y;
  }
  #pragma unroll
  for (int s = 0; s < 2; s++){
    int e = (s == 0) ? e0 : e1;
    if (e != 0 && e != 2) continue;
    float gain, decay, cmax;
    if (e == 0){ gain = *hg_gain; decay = *hg_decay; cmax = 3.0f; }
    else       { gain = *lg_gain; decay = *lg_decay; cmax = 1.0f; }
    float filt = (1.0f - expf(-gain*fg)) * expf(-decay*fg);
    filt = fminf(fmaxf(filt, 0.0f), cmax) * (1.0f/16384.0f);
    int bs = b*2 + s;
    const float* axp = (s == 0) ? a0x : a1x;
    const float* ayp = (s == 0) ? a0y : a1y;
    #pragma unroll
    for (int r4 = 0; r4 < 4; r4++){
      int r = g*4 + r4;
      Y[((size_t)(bs*32 + r))*8320 + j*128 + i] = make_float2(axp[r4]*filt, ayp[r4]*filt);
    }
  }
}

// Fused inverse 2-D FFT per (bs,r) for freq slots; body written IN PLACE. 512 threads.
__global__ __launch_bounds__(512) void k_ifft2(float2* __restrict__ Y, const int* __restrict__ slot_e){
  int blk = blockIdx.x;
  int bs = blk >> 5, r = blk & 31;
  int es = slot_e[bs];
  if (es == 1 || es == 3) return;     // conv slots skip
  __shared__ float2 z[8192];
  int t = threadIdx.x; int lane = t & 63, wv = t >> 6;
  Tw7 T; init_tw(T, lane);
  float2* Yb = Y + (size_t)(bs*32 + r) * 8320;

  // load; row 0 packed: P[i] = Y[0][i] + i*Y[64][i]
  for (int idx = t; idx < 8192; idx += 512){
    int j = idx >> 7, i = idx & 127;
    if (j == 0){
      float2 y0 = Yb[i];
      float2 y6 = Yb[8192 + i];
      z[LIDX(0,i)] = make_float2(y0.x - y6.y, y0.y + y6.x);
    } else {
      z[LIDX(j,i)] = Yb[idx];
    }
  }
  __syncthreads();

  // inverse column FFTs (unnormalized), in place per column
  #pragma unroll
  for (int k = 0; k < 8; k++){
    int jj = wv*8 + k;
    float2 z0 = z[LIDX(jj,lane)], z1 = z[LIDX(jj,lane+64)];
    cpx a{z0.x, -z0.y}, b{z1.x, -z1.y};
    fft128(a, b, lane, T);
    int i0 = 2*br6(lane);
    z[LIDX(jj,i0)]   = make_float2(a.x, -a.y);
    z[LIDX(jj,i0+1)] = make_float2(b.x, -b.y);
  }
  __syncthreads();

  // inverse row transform: two real output rows per complex inverse FFT
  float* body = (float*)Yb;
  #pragma unroll 2
  for (int k = 0; k < 8; k++){
    int p = wv*8 + k;
    int h = 2*p, h1 = 2*p + 1;
    cpx a, b;
    if (lane == 0){
      float2 c0 = z[LIDX(0,h)], c1 = z[LIDX(0,h1)];
      a = { c0.x, c1.x };
      b = { c0.y, c1.y };
    } else {
      float2 yh = z[LIDX(lane,h)], y1 = z[LIDX(lane,h1)];
      a = { yh.x - y1.y, yh.y + y1.x };
      int lm = 64 - lane;
      float2 zh = z[LIDX(lm,h)], z1_ = z[LIDX(lm,h1)];
      b = { zh.x + z1_.y, z1_.x - zh.y };
    }
    a.y = -a.y; b.y = -b.y;        // conj
    fft128(a, b, lane, T);
    int n0 = 2*br6(lane);
    body[h*128 + n0]      = a.x;   // conj on output: real part
    body[h1*128 + n0]     = -a.y;
    body[h*128 + n0 + 1]  = b.x;
    body[h1*128 + n0 + 1] = -b.y;
  }
}

// A[bs][r] = P0[e_s] x[b]  for conv slots only (weight rows contiguous -> s_load ok).
__global__ __launch_bounds__(256) void k_projA(const float* __restrict__ x, const float* __restrict__ proj0,
    const int* __restrict__ slot_e, float* __restrict__ A){
  int b = blockIdx.y;
  int e0 = slot_e[b*2 + 0], e1 = slot_e[b*2 + 1];
  bool c0 = (e0 == 1) || (e0 == 3);
  bool c1 = (e1 == 1) || (e1 == 3);
  if (!c0 && !c1) return;
  int hw = blockIdx.x * 256 + threadIdx.x;
  const float* xb = x + (size_t)b*64*16384 + hw;
  float xv[64];
  #pragma unroll
  for (int c = 0; c < 64; c++) xv[c] = xb[(size_t)c*16384];
  if (c0){
    const float* W = proj0 + __builtin_amdgcn_readfirstlane(e0)*2048;
    float* Ab = A + (size_t)(b*2 + 0)*32*16384 + hw;
    for (int r = 0; r < 32; r++){
      float a = 0.f;
      #pragma unroll
      for (int c = 0; c < 64; c++) a += W[r*64 + c] * xv[c];
      Ab[(size_t)r*16384] = a;
    }
  }
  if (c1){
    const float* W = proj0 + __builtin_amdgcn_readfirstlane(e1)*2048;
    float* Ab = A + (size_t)(b*2 + 1)*32*16384 + hw;
    for (int r = 0; r < 32; r++){
      float a = 0.f;
      #pragma unroll
      for (int c = 0; c < 64; c++) a += W[r*64 + c] * xv[c];
      Ab[(size_t)r*16384] = a;
    }
  }
}

// Expert 1 fused: dw3 -> gelu -> dw3, LDS-tiled (16 out rows x 128)
__global__ __launch_bounds__(256) void k_conv3(const float* __restrict__ A, float* __restrict__ bodyY,
    const float* __restrict__ w1g, const float* __restrict__ b1g,
    const float* __restrict__ w2g, const float* __restrict__ b2g,
    const int* __restrict__ slot_of){
  int by = blockIdx.y; int b = by >> 5, r = by & 31;
  int slot = slot_of[b*4 + 1];
  if (slot < 0) return;
  int bs = b*2 + slot;
  int h0 = blockIdx.x * 16;
  int t = threadIdx.x;
  __shared__ float sin_[20*130];
  __shared__ float st[18*130];
  for (int i = t; i < 20*130; i += 256) sin_[i] = 0.f;
  for (int i = t; i < 18*130; i += 256) st[i] = 0.f;
  float w1[9], w2[9];
  #pragma unroll
  for (int k = 0; k < 9; k++){ w1[k] = w1g[r*9 + k]; w2[k] = w2g[r*9 + k]; }
  float b1 = b1g[r], b2 = b2g[r];
  __syncthreads();
  const float* ip = A + (size_t)(bs*32 + r)*16384;
  for (int idx = t; idx < 20*128; idx += 256){
    int li = idx >> 7, ww = idx & 127;
    int ih = h0 - 2 + li;
    if (ih >= 0 && ih < 128) sin_[li*130 + 1 + ww] = ip[ih*128 + ww];
  }
  __syncthreads();
  for (int idx = t; idx < 18*128; idx += 256){
    int li = idx >> 7, ww = idx & 127;
    int hs = h0 - 1 + li;
    if (hs >= 0 && hs < 128){
      float acc = b1;
      #pragma unroll
      for (int kh = 0; kh < 3; kh++)
        #pragma unroll
        for (int kw = 0; kw < 3; kw++)
          acc += w1[kh*3 + kw] * sin_[(li + kh)*130 + ww + kw];
      st[li*130 + 1 + ww] = gelu_exact(acc);
    }
  }
  __syncthreads();
  float* op = bodyY + (size_t)(bs*32 + r)*16640;
  for (int idx = t; idx < 16*128; idx += 256){
    int li = idx >> 7, ww = idx & 127;
    int ho = h0 + li;
    float acc = b2;
    #pragma unroll
    for (int kh = 0; kh < 3; kh++)
      #pragma unroll
      for (int kw = 0; kw < 3; kw++)
        acc += w2[kh*3 + kw] * st[(li + kh)*130 + ww + kw];
    op[ho*128 + ww] = acc;
  }
}

// Expert 3 fused: dw7 -> gelu -> avgpool3 (count_include_pad)
__global__ __launch_bounds__(256) void k_conv7(const float* __restrict__ A, float* __restrict__ bodyY,
    const float* __restrict__ wg, const float* __restrict__ bg,
    const int* __restrict__ slot_of){
  int by = blockIdx.y; int b = by >> 5, r = by & 31;
  int slot = slot_of[b*4 + 3];
  if (slot < 0) return;
  int bs = b*2 + slot;
  int h0 = blockIdx.x * 16;
  int t = threadIdx.x;
  __shared__ float sin_[24*134];
  __shared__ float st[18*134];
  __shared__ float wsh[49];
  for (int i = t; i < 24*134; i += 256) sin_[i] = 0.f;
  for (int i = t; i < 18*134; i += 256) st[i] = 0.f;
  if (t < 49) wsh[t] = wg[r*49 + t];
  float bias = bg[r];
  __syncthreads();
  const float* ip = A + (size_t)(bs*32 + r)*16384;
  for (int idx = t; idx < 24*128; idx += 256){
    int li = idx >> 7, ww = idx & 127;
    int ih = h0 - 4 + li;
    if (ih >= 0 && ih < 128) sin_[li*134 + 3 + ww] = ip[ih*128 + ww];
  }
  __syncthreads();
  for (int idx = t; idx < 18*128; idx += 256){
    int li = idx >> 7, ww = idx & 127;
    int hs = h0 - 1 + li;
    if (hs >= 0 && hs < 128){
      float acc = bias;
      #pragma unroll
      for (int kh = 0; kh < 7; kh++)
        #pragma unroll
        for (int kw = 0; kw < 7; kw++)
          acc += wsh[kh*7 + kw] * sin_[(li + kh)*134 + ww + kw];
      st[li*134 + 1 + ww] = gelu_exact(acc);
    }
  }
  __syncthreads();
  float* op = bodyY + (size_t)(bs*32 + r)*16640;
  for (int idx = t; idx < 16*128; idx += 256){
    int li = idx >> 7, ww = idx & 127;
    int ho = h0 + li;
    float acc = 0.f;
    #pragma unroll
    for (int kh = 0; kh < 3; kh++)
      #pragma unroll
      for (int kw = 0; kw < 3; kw++)
        acc += st[(li + kh)*134 + ww + kw];
    op[ho*128 + ww] = acc * (1.0f/9.0f);
  }
}

// Final: out[b,c] = (g0+g1)*x[b,c] + sum_s g_s * P2[e_s][c,:] (body_s * silu(P1[e_s] x))
// Weights served from LDS broadcast (P1 transposed, P2 natural layout).
__global__ __launch_bounds__(256) void k_combine(const float* __restrict__ x, const float* __restrict__ bodyY,
    const float* __restrict__ proj1, const float* __restrict__ proj2,
    const int* __restrict__ slot_e, const float* __restrict__ slot_g,
    float* __restrict__ out){
  int b = blockIdx.y;
  int t = threadIdx.x;
  int hw = blockIdx.x * 256 + t;
  int ea = __builtin_amdgcn_readfirstlane(slot_e[b*2 + 0]);
  int eb = __builtin_amdgcn_readfirstlane(slot_e[b*2 + 1]);
  float ga = slot_g[b*2 + 0], gb = slot_g[b*2 + 1];
  float gs = ga + gb;
  __shared__ __align__(16) float w1t[2][64*36];   // P1^T: [c][r], pad 36 (144B rows, 16B-aligned)
  __shared__ __align__(16) float w2s[2][2048];    // P2 natural [c][r]
  {
    const float* P1a = proj1 + ea*2048;
    const float* P1b = proj1 + eb*2048;
    const float* P2a = proj2 + ea*2048;
    const float* P2b = proj2 + eb*2048;
    for (int idx = t; idx < 2048; idx += 256){
      int r = idx >> 6, c = idx & 63;
      w1t[0][c*36 + r] = P1a[idx];
      w1t[1][c*36 + r] = P1b[idx];
      w2s[0][idx] = P2a[idx];
      w2s[1][idx] = P2b[idx];
    }
  }
  __syncthreads();
  const float* xb = x + (size_t)b*64*16384 + hw;

  float Ga[32], Gb[32];
  #pragma unroll
  for (int r = 0; r < 32; r++){ Ga[r] = 0.f; Gb[r] = 0.f; }
  for (int c = 0; c < 64; c++){
    float xc = xb[(size_t)c*16384];
    const float4* wa = (const float4*)&w1t[0][c*36];
    const float4* wb = (const float4*)&w1t[1][c*36];
    #pragma unroll
    for (int q = 0; q < 8; q++){
      float4 va = wa[q], vb = wb[q];
      Ga[q*4+0] += va.x*xc; Ga[q*4+1] += va.y*xc; Ga[q*4+2] += va.z*xc; Ga[q*4+3] += va.w*xc;
      Gb[q*4+0] += vb.x*xc; Gb[q*4+1] += vb.y*xc; Gb[q*4+2] += vb.z*xc; Gb[q*4+3] += vb.w*xc;
    }
  }
  // G -> body * silu(G)
  const float* Ba = bodyY + (size_t)(b*2 + 0)*32*16640 + hw;
  const float* Bb = bodyY + (size_t)(b*2 + 1)*32*16640 + hw;
  #pragma unroll
  for (int r = 0; r < 32; r++){
    Ga[r] = Ba[(size_t)r*16640] * silu(Ga[r]);
    Gb[r] = Bb[(size_t)r*16640] * silu(Gb[r]);
  }
  float* ob = out + (size_t)b*64*16384 + hw;
  for (int c = 0; c < 64; c++){
    float xc = xb[(size_t)c*16384];
    const float4* wa = (const float4*)&w2s[0][c*32];
    const float4* wb = (const float4*)&w2s[1][c*32];
    float acc0 = 0.f, acc1 = 0.f;
    #pragma unroll
    for (int q = 0; q < 8; q++){
      float4 va = wa[q], vb = wb[q];
      acc0 += va.x*Ga[q*4+0] + va.y*Ga[q*4+1] + va.z*Ga[q*4+2] + va.w*Ga[q*4+3];
      acc1 += vb.x*Gb[q*4+0] + vb.y*Gb[q*4+1] + vb.z*Gb[q*4+2] + vb.w*Gb[q*4+3];
    }
    ob[(size_t)c*16384] = gs*xc + ga*acc0 + gb*acc1;
  }
}

} // namespace

extern "C" void kernel_launch(void* const* d_in, const int* in_sizes, int n_in,
                              void* d_out, int out_size, void* d_ws, size_t ws_size,
                              hipStream_t stream) {
  (void)in_sizes; (void)n_in; (void)out_size; (void)ws_size;
  const float* x        = (const float*)d_in[0];
  const float* noise    = (const float*)d_in[1];
  const float* gate_w   = (const float*)d_in[2];
  const float* fg_w1    = (const float*)d_in[3];
  const float* fg_b1    = (const float*)d_in[4];
  const float* fg_w2    = (const float*)d_in[5];
  const float* proj0    = (const float*)d_in[6];
  const float* proj1    = (const float*)d_in[7];
  const float* proj2    = (const float*)d_in[8];
  const float* hg_gain  = (const float*)d_in[9];
  const float* hg_decay = (const float*)d_in[10];
  const float* hf_w1    = (const float*)d_in[11];
  const float* hf_b1    = (const float*)d_in[12];
  const float* hf_w2    = (const float*)d_in[13];
  const float* hf_b2    = (const float*)d_in[14];
  const float* lg_gain  = (const float*)d_in[15];
  const float* lg_decay = (const float*)d_in[16];
  const float* lf_w     = (const float*)d_in[17];
  const float* lf_b     = (const float*)d_in[18];
  float* out = (float*)d_out;

  // ws (floats):
  //  [0, 17039360)            X spectra [1024][65][128] f2 ; later overlaid by A [32 bs][32 r][16384]
  //  [17039360, 34078720)     Yspec/body [32 bs][32 r][65*128 f2]
  //  tail: xmean 1024 | part_w 65536 | slot_g 32 | slot_e 32 (int) | slot_of 64 (int)
  float* ws = (float*)d_ws;
  float2* X  = (float2*)ws;
  float*  A  = ws;
  float*  Yf = ws + 17039360;
  float2* Y2 = (float2*)Yf;
  float*  tail   = ws + 34078720;
  float*  xmean  = tail;
  float*  part_w = xmean + 1024;
  float*  slot_g = part_w + 65536;
  int*    slot_e = (int*)(slot_g + 32);
  int*    slot_of = slot_e + 32;

  // routing inputs (xmean from spectrum DC)
  k_fft2fwd<<<1024, 512, 0, stream>>>(x, X, part_w, xmean);
  k_routing<<<1, 128, 0, stream>>>(xmean, part_w, noise, gate_w, fg_w1, fg_b1, fg_w2,
                                   slot_e, slot_of, slot_g);

  // frequency-domain projections, both freq experts in one X pass
  k_projfreq<<<dim3(4,65,16), 256, 0, stream>>>(X, proj0, Y2, slot_e,
                                                hg_gain, hg_decay, lg_gain, lg_decay);

  // A for conv slots (overlays X; X dead after projfreq)
  k_projA<<<dim3(64,16), 256, 0, stream>>>(x, proj0, slot_e, A);

  // inverse FFTs for freq slots (bodies in place in Yspec)
  k_ifft2<<<1024, 512, 0, stream>>>(Y2, slot_e);

  // conv experts (bodies into Yspec slots)
  k_conv3<<<dim3(8,512), 256, 0, stream>>>(A, Yf, hf_w1, hf_b1, hf_w2, hf_b2, slot_of);
  k_conv7<<<dim3(8,512), 256, 0, stream>>>(A, Yf, lf_w, lf_b, slot_of);

  // final combine (includes shortcut and gating; writes out exactly once)
  k_combine<<<dim3(64,16), 256, 0, stream>>>(x, Yf, proj1, proj2, slot_e, slot_g, out);
}